// Round 6
// baseline (674.251 us; speedup 1.0000x reference)
//
#include <hip/hip_runtime.h>
#include <hip/hip_bf16.h>
#include <hip/hip_cooperative_groups.h>

namespace cg = cooperative_groups;

typedef __hip_bfloat16 bf16;
typedef __hip_bfloat162 bf162;
typedef __attribute__((ext_vector_type(8))) short short8;   // 8 bf16 (4 VGPRs)
typedef __attribute__((ext_vector_type(4))) float f32x4;    // MFMA C/D

#define NN 100000
#define NE 1600000
#define ETOT (NE + NN)
#define DIM 128
#define HEADS 8

// ---- bucket-sort CSR build parameters ----
#define BSH 9                                   // bucket = dest >> 9 (512 dests)
#define NBUK ((NN + 511) >> BSH)                // 196
#define EPB 2048                                // edges per partition block
#define B1 ((ETOT + EPB - 1) / EPB)             // 831 blocks
#define MAXPER 40                               // regs/thread in bucket phase
                                                // cap 10240 = mean 8704 + 16.5 sigma

__device__ __forceinline__ float lrelu(float v) { return v > 0.f ? v : 0.2f * v; }

__device__ __forceinline__ float load1(const void* p, int i, int isbf) {
    return isbf ? __bfloat162float(((const bf16*)p)[i]) : ((const float*)p)[i];
}
__device__ __forceinline__ float2 load2(const void* p, size_t pairIdx, int isbf) {
    if (isbf) return __bfloat1622float2(((const bf162*)p)[pairIdx]);
    return ((const float2*)p)[pairIdx];
}
__device__ __forceinline__ short f2bf(float f) {
    bf16 h = __float2bfloat16(f);
    return *reinterpret_cast<short*>(&h);
}

// ---------------------------------------------------------------------------
// K1: MFMA projection with detect + aug FOLDED IN (one launch fewer each).
// Every block: (1) detect dtype from W (L2-hot), (2) stage W into Wf,
// (3) compute the 16 augmented rows Was/Wad from the staged Wf directly into
// the jt=8 B-tile (redundantly per block; ~128 LDS MACs/thread), (4) MFMA,
// (5) LDS-staged coalesced writeback.  Block 0 publishes flag for gather.
// ---------------------------------------------------------------------------
__global__ __launch_bounds__(256) void proj_mfma_kernel(
    const void* __restrict__ x, const void* __restrict__ W,
    const void* __restrict__ bproj, const void* __restrict__ atts,
    const void* __restrict__ attd, int* __restrict__ flag,
    bf16* __restrict__ xh, float* __restrict__ asrc, float* __restrict__ adst)
{
    __shared__ short8 Wf[2304];                 // 36 KB: 9 B-tiles (reused as stage)
    __shared__ float bsh[DIM], csh[16];
    __shared__ float av[256];                   // atts | attd
    __shared__ float red[256];

    const int tid = threadIdx.x;

    // ---- detect (same sampling as the passing config) ----
    {
        const bf16* wb = (const bf16*)W;
        float m = 0.f;
        for (int i = tid; i < 8192; i += 256) {
            float v = fabsf(__bfloat162float(wb[i]));
            if (!(v < 1e30f)) v = 1e30f;
            m = fmaxf(m, v);
        }
        red[tid] = m;
        __syncthreads();
        for (int s = 128; s > 0; s >>= 1) {
            if (tid < s) red[tid] = fmaxf(red[tid], red[tid + s]);
            __syncthreads();
        }
    }
    const int isbf = (red[0] < 1.0f) ? 1 : 0;
    if (blockIdx.x == 0 && tid == 0) *flag = isbf;

    // ---- stage W into fragment order ----
    for (int c = tid; c < 2048; c += 256) {
        int j = c >> 4, kc = c & 15;
        int kb = kc >> 2, quad = kc & 3;
        int lane = quad * 16 + (j & 15);
        int jt = j >> 4;
        short8 v;
        if (isbf) {
            v = ((const short8*)W)[c];          // 8 bf16 at W[j][kc*8]
        } else {
            const float* wp = (const float*)W + (size_t)j * DIM + kc * 8;
            #pragma unroll
            for (int i = 0; i < 8; ++i) v[i] = f2bf(wp[i]);
        }
        Wf[(jt * 4 + kb) * 64 + lane] = v;
    }
    if (tid < DIM) bsh[tid] = load1(bproj, tid, isbf);
    av[tid] = (tid < 128) ? load1(atts, tid, isbf)
                          : load1(attd, tid - 128, isbf);
    __syncthreads();

    // ---- compute augmented tile from staged Wf (each thread one short8) ----
    {
        const int kb = tid >> 6;                // 0..3
        const int lane = tid & 63;
        const int quad = (tid >> 4) & 3;
        const int j2 = tid & 15;                // aug row: 0..7 src, 8..15 dst
        const int h = j2 & 7;
        const int ao = (j2 < 8) ? 0 : 128;
        short8 vv;
        #pragma unroll
        for (int c = 0; c < 8; ++c) {
            float s = 0.f;
            #pragma unroll
            for (int t = 0; t < 16; ++t) {
                // W[h*16+t][(kb*4+quad)*8 + c] from Wf
                const bf16* wp = (const bf16*)&Wf[(h * 4 + kb) * 64 + quad * 16 + t];
                s += av[ao + h * 16 + t] * __bfloat162float(wp[c]);
            }
            vv[c] = f2bf(s);
        }
        Wf[(32 + kb) * 64 + lane] = vv;
    }
    if (tid < 16) {
        const int h = tid & 7;
        const int ao = (tid < 8) ? 0 : 128;
        float s = 0.f;
        #pragma unroll
        for (int t = 0; t < 16; ++t)
            s += bsh[h * 16 + t] * av[ao + h * 16 + t];
        csh[tid] = s;
    }
    __syncthreads();

    const int w = tid >> 6;
    const int l = tid & 63;
    const int quad = l >> 4, mr = l & 15;
    const int n0 = blockIdx.x * 64 + w * 16;    // wave's first node
    const int nArd = min(n0 + mr, NN - 1);      // clamped A-frag row

    short8 afr[4];
    if (isbf) {
        const short8* xp = (const short8*)x + (size_t)nArd * 16;
        #pragma unroll
        for (int kb = 0; kb < 4; ++kb) afr[kb] = xp[kb * 4 + quad];
    } else {
        const float* xp = (const float*)x + (size_t)nArd * DIM;
        #pragma unroll
        for (int kb = 0; kb < 4; ++kb) {
            const float* cp = xp + kb * 32 + quad * 8;
            float4 c0 = *(const float4*)cp;
            float4 c1 = *(const float4*)(cp + 4);
            short8 v;
            v[0] = f2bf(c0.x); v[1] = f2bf(c0.y); v[2] = f2bf(c0.z); v[3] = f2bf(c0.w);
            v[4] = f2bf(c1.x); v[5] = f2bf(c1.y); v[6] = f2bf(c1.z); v[7] = f2bf(c1.w);
            afr[kb] = v;
        }
    }

    // ---- MFMA phase: keep all 8 xh-tiles in registers ----
    f32x4 accs[8];
    #pragma unroll
    for (int jt = 0; jt < 8; ++jt) {
        f32x4 acc = {0.f, 0.f, 0.f, 0.f};
        #pragma unroll
        for (int kb = 0; kb < 4; ++kb) {
            short8 b = Wf[(jt * 4 + kb) * 64 + l];
            acc = __builtin_amdgcn_mfma_f32_16x16x32_bf16(afr[kb], b, acc, 0, 0, 0);
        }
        accs[jt] = acc;
    }
    // augmented tile (uses Wf -> must finish before the stage overlay)
    f32x4 acca = {0.f, 0.f, 0.f, 0.f};
    #pragma unroll
    for (int kb = 0; kb < 4; ++kb) {
        short8 b = Wf[(32 + kb) * 64 + l];
        acca = __builtin_amdgcn_mfma_f32_16x16x32_bf16(afr[kb], b, acca, 0, 0, 0);
    }

    __syncthreads();                            // all waves done reading Wf

    // ---- stage 16x128 bf16 tile in LDS (stride 136 elems = 272B) ----
    bf16* sw = ((bf16*)Wf) + w * (16 * 136);    // 4352 B per wave
    #pragma unroll
    for (int jt = 0; jt < 8; ++jt) {
        const int jj = jt * 16 + mr;
        const float bv = bsh[jj];
        #pragma unroll
        for (int r = 0; r < 4; ++r)
            sw[(quad * 4 + r) * 136 + jj] = __float2bfloat16(accs[jt][r] + bv);
    }
    // ---- coalesced write-back: 4 x short8 per lane ----
    #pragma unroll
    for (int g = 0; g < 4; ++g) {
        const int row = g * 4 + (l >> 4);       // 0..15
        const int n = n0 + row;
        if (n < NN)
            *((short8*)(xh + (size_t)n * DIM) + (l & 15)) =
                *(const short8*)(sw + row * 136 + (l & 15) * 8);
    }

    // ---- asrc/adst from the augmented tile ----
    {
        const float cst = csh[mr];
        #pragma unroll
        for (int r = 0; r < 4; ++r) {
            const int n = n0 + quad * 4 + r;
            if (n < NN) {
                float v = acca[r] + cst;
                if (mr < 8) asrc[n * HEADS + mr] = v;
                else        adst[n * HEADS + (mr - 8)] = v;
            }
        }
    }
}

// ---------------------------------------------------------------------------
// CSR build: ONE cooperative kernel, 5 phases with grid.sync between them.
// Phase math is bit-identical to the round-5 chain; only scheduling changed
// (4 grid syncs replace 4 full kernel-launch drains).
// __launch_bounds__(256,4) caps VGPR at 128 -> 4 blocks/CU -> 1024 >= B1=831
// co-resident, so the cooperative launch is guaranteed to fit.
// ---------------------------------------------------------------------------
__global__ __launch_bounds__(256, 4) void csr_coop_kernel(
    const int* __restrict__ ei, int* __restrict__ cntmat,
    int* __restrict__ cntpre, int* __restrict__ btot,
    int* __restrict__ bbase, int* __restrict__ esrc,
    int* __restrict__ rowstart)
{
    cg::grid_group grid = cg::this_grid();
    __shared__ int sh[1028];                    // union across phases
    const int t = threadIdx.x, b = blockIdx.x;

    // ================= phase 1: coarse-bucket count =================
    for (int i = t; i < NBUK; i += 256) sh[i] = 0;
    __syncthreads();
    {
        const int base = b * EPB;
        #pragma unroll
        for (int it = 0; it < EPB / 1024; ++it) {
            const int e = base + it * 1024 + t * 4;     // ETOT%4==0, NE%4==0
            if (e < ETOT) {
                int4 d4;
                if (e < NE) {
                    d4 = *(const int4*)(ei + NE + e);
                } else {
                    d4.x = e - NE; d4.y = d4.x + 1; d4.z = d4.x + 2; d4.w = d4.x + 3;
                }
                atomicAdd(&sh[d4.x >> BSH], 1);
                atomicAdd(&sh[d4.y >> BSH], 1);
                atomicAdd(&sh[d4.z >> BSH], 1);
                atomicAdd(&sh[d4.w >> BSH], 1);
            }
        }
    }
    __syncthreads();
    for (int k = t; k < NBUK; k += 256) cntmat[k * B1 + b] = sh[k];
    grid.sync();

    // ========== phase 2: per-bucket scan over block counts ==========
    if (b < NBUK) {
        const int k = b;
        int v[4];
        int s = 0;
        #pragma unroll
        for (int j = 0; j < 4; ++j) {
            const int c = t * 4 + j;
            v[j] = (c < B1) ? cntmat[k * B1 + c] : 0;
            s += v[j];
        }
        const int l = t & 63, w = t >> 6;
        int inc = s;
        #pragma unroll
        for (int off = 1; off < 64; off <<= 1) {
            int u = __shfl_up(inc, off);
            if (l >= off) inc += u;
        }
        if (l == 63) sh[1024 + w] = inc;
        __syncthreads();
        int add = 0;
        #pragma unroll
        for (int i = 0; i < 4; ++i) if (i < w) add += sh[1024 + i];
        int run = add + inc - s;
        #pragma unroll
        for (int j = 0; j < 4; ++j) {
            const int c = t * 4 + j;
            if (c < B1) cntpre[k * B1 + c] = run;
            run += v[j];
        }
        if (t == 255) btot[k] = add + inc;
    }
    grid.sync();

    // ============ phase 3: scan of bucket totals (block 0) ============
    if (b == 0) {
        const int v = (t < NBUK) ? btot[t] : 0;
        const int l = t & 63, w = t >> 6;
        int inc = v;
        #pragma unroll
        for (int off = 1; off < 64; off <<= 1) {
            int u = __shfl_up(inc, off);
            if (l >= off) inc += u;
        }
        if (l == 63) sh[1024 + w] = inc;
        __syncthreads();
        int add = 0;
        #pragma unroll
        for (int i = 0; i < 4; ++i) if (i < w) add += sh[1024 + i];
        if (t < NBUK) bbase[t] = add + inc - v;
        if (t == 0) rowstart[NN] = ETOT;
    }
    grid.sync();

    // ================= phase 4: bucket-grouped scatter =================
    for (int k = t; k < NBUK; k += 256) sh[k] = bbase[k] + cntpre[k * B1 + b];
    __syncthreads();
    {
        const int base = b * EPB;
        #pragma unroll
        for (int it = 0; it < EPB / 1024; ++it) {
            const int e = base + it * 1024 + t * 4;
            if (e < ETOT) {
                int4 d4, s4;
                if (e < NE) {
                    s4 = *(const int4*)(ei + e);
                    d4 = *(const int4*)(ei + NE + e);
                } else {
                    s4.x = e - NE; s4.y = s4.x + 1; s4.z = s4.x + 2; s4.w = s4.x + 3;
                    d4 = s4;
                }
                const int p0 = atomicAdd(&sh[d4.x >> BSH], 1);
                const int p1 = atomicAdd(&sh[d4.y >> BSH], 1);
                const int p2 = atomicAdd(&sh[d4.z >> BSH], 1);
                const int p3 = atomicAdd(&sh[d4.w >> BSH], 1);
                esrc[p0] = s4.x | ((d4.x & 511) << 17);
                esrc[p1] = s4.y | ((d4.y & 511) << 17);
                esrc[p2] = s4.z | ((d4.z & 511) << 17);
                esrc[p3] = s4.w | ((d4.w & 511) << 17);
            }
        }
    }
    grid.sync();

    // ============== phase 5: in-bucket sort (blocks < NBUK) ==============
    if (b < NBUK) {
        const int k = b;
        const int start = bbase[k];
        const int end = (k == NBUK - 1) ? ETOT : bbase[k + 1];

        sh[t] = 0;                              // hist = sh[0..511]
        sh[t + 256] = 0;
        __syncthreads();

        int v[MAXPER];
        #pragma unroll
        for (int j = 0; j < MAXPER; ++j) {
            const int idx = start + j * 256 + t;
            v[j] = (idx < end) ? esrc[idx] : -1;
        }
        #pragma unroll
        for (int j = 0; j < MAXPER; ++j)
            if (v[j] >= 0) atomicAdd(&sh[(v[j] >> 17) & 511], 1);
        __syncthreads();

        const int h0 = sh[2 * t], h1 = sh[2 * t + 1];
        const int pv = h0 + h1;
        const int l = t & 63, w = t >> 6;
        int inc = pv;
        #pragma unroll
        for (int off = 1; off < 64; off <<= 1) {
            int u = __shfl_up(inc, off);
            if (l >= off) inc += u;
        }
        if (l == 63) sh[1024 + w] = inc;
        __syncthreads();
        int add = 0;
        #pragma unroll
        for (int i = 0; i < 4; ++i) if (i < w) add += sh[1024 + i];
        const int ex = add + inc - pv;
        sh[512 + 2 * t] = ex;                   // pre = sh[512..1023]
        sh[512 + 2 * t + 1] = ex + h0;

        const int d0 = (k << BSH) + 2 * t;
        if (d0 < NN)     rowstart[d0]     = start + ex;
        if (d0 + 1 < NN) rowstart[d0 + 1] = start + ex + h0;
        __syncthreads();

        #pragma unroll
        for (int j = 0; j < MAXPER; ++j) {
            if (v[j] >= 0) {
                const int pos = atomicAdd(&sh[512 + ((v[j] >> 17) & 511)], 1);
                esrc[start + pos] = v[j] & 0x1FFFF;
            }
        }
    }
}

// ---------------------------------------------------------------------------
// Fallback chain (round-5, used only if cooperative launch is rejected).
// ---------------------------------------------------------------------------
__global__ __launch_bounds__(256) void csr_count_kernel(const int* __restrict__ ei,
                                                        int* __restrict__ cntmat)
{
    __shared__ int cnt[NBUK];
    const int t = threadIdx.x, b = blockIdx.x;
    for (int i = t; i < NBUK; i += 256) cnt[i] = 0;
    __syncthreads();
    const int base = b * EPB;
    #pragma unroll
    for (int it = 0; it < EPB / 1024; ++it) {
        const int e = base + it * 1024 + t * 4;
        if (e < ETOT) {
            int4 d4;
            if (e < NE) {
                d4 = *(const int4*)(ei + NE + e);
            } else {
                d4.x = e - NE; d4.y = d4.x + 1; d4.z = d4.x + 2; d4.w = d4.x + 3;
            }
            atomicAdd(&cnt[d4.x >> BSH], 1);
            atomicAdd(&cnt[d4.y >> BSH], 1);
            atomicAdd(&cnt[d4.z >> BSH], 1);
            atomicAdd(&cnt[d4.w >> BSH], 1);
        }
    }
    __syncthreads();
    for (int k = t; k < NBUK; k += 256) cntmat[k * B1 + b] = cnt[k];
}

__global__ __launch_bounds__(256) void csr_colscan_kernel(const int* __restrict__ cntmat,
                                                          int* __restrict__ cntpre,
                                                          int* __restrict__ btot)
{
    const int k = blockIdx.x, t = threadIdx.x;
    int v[4];
    int s = 0;
    #pragma unroll
    for (int j = 0; j < 4; ++j) {
        const int c = t * 4 + j;
        v[j] = (c < B1) ? cntmat[k * B1 + c] : 0;
        s += v[j];
    }
    const int l = t & 63, w = t >> 6;
    int inc = s;
    #pragma unroll
    for (int off = 1; off < 64; off <<= 1) {
        int u = __shfl_up(inc, off);
        if (l >= off) inc += u;
    }
    __shared__ int wt[4];
    if (l == 63) wt[w] = inc;
    __syncthreads();
    int add = 0;
    #pragma unroll
    for (int i = 0; i < 4; ++i) if (i < w) add += wt[i];
    int run = add + inc - s;
    #pragma unroll
    for (int j = 0; j < 4; ++j) {
        const int c = t * 4 + j;
        if (c < B1) cntpre[k * B1 + c] = run;
        run += v[j];
    }
    if (t == 255) btot[k] = add + inc;
}

__global__ __launch_bounds__(256) void csr_base_kernel(const int* __restrict__ btot,
                                                       int* __restrict__ bbase,
                                                       int* __restrict__ rowstart)
{
    const int t = threadIdx.x;
    const int v = (t < NBUK) ? btot[t] : 0;
    const int l = t & 63, w = t >> 6;
    int inc = v;
    #pragma unroll
    for (int off = 1; off < 64; off <<= 1) {
        int u = __shfl_up(inc, off);
        if (l >= off) inc += u;
    }
    __shared__ int wt[4];
    if (l == 63) wt[w] = inc;
    __syncthreads();
    int add = 0;
    #pragma unroll
    for (int i = 0; i < 4; ++i) if (i < w) add += wt[i];
    if (t < NBUK) bbase[t] = add + inc - v;
    if (t == 0) rowstart[NN] = ETOT;
}

__global__ __launch_bounds__(256) void csr_scatter_kernel(const int* __restrict__ ei,
                                                          const int* __restrict__ cntpre,
                                                          const int* __restrict__ bbase,
                                                          int* __restrict__ esrc)
{
    __shared__ int cur[NBUK];
    const int t = threadIdx.x, b = blockIdx.x;
    for (int k = t; k < NBUK; k += 256) cur[k] = bbase[k] + cntpre[k * B1 + b];
    __syncthreads();
    const int base = b * EPB;
    #pragma unroll
    for (int it = 0; it < EPB / 1024; ++it) {
        const int e = base + it * 1024 + t * 4;
        if (e < ETOT) {
            int4 d4, s4;
            if (e < NE) {
                s4 = *(const int4*)(ei + e);
                d4 = *(const int4*)(ei + NE + e);
            } else {
                s4.x = e - NE; s4.y = s4.x + 1; s4.z = s4.x + 2; s4.w = s4.x + 3;
                d4 = s4;
            }
            const int p0 = atomicAdd(&cur[d4.x >> BSH], 1);
            const int p1 = atomicAdd(&cur[d4.y >> BSH], 1);
            const int p2 = atomicAdd(&cur[d4.z >> BSH], 1);
            const int p3 = atomicAdd(&cur[d4.w >> BSH], 1);
            esrc[p0] = s4.x | ((d4.x & 511) << 17);
            esrc[p1] = s4.y | ((d4.y & 511) << 17);
            esrc[p2] = s4.z | ((d4.z & 511) << 17);
            esrc[p3] = s4.w | ((d4.w & 511) << 17);
        }
    }
}

__global__ __launch_bounds__(256) void csr_bucket_kernel(const int* __restrict__ bbase,
                                                         int* __restrict__ esrc,
                                                         int* __restrict__ rowstart)
{
    __shared__ int hist[512];
    __shared__ int pre[512];
    __shared__ int wt[4];
    const int k = blockIdx.x, t = threadIdx.x;
    const int start = bbase[k];
    const int end = (k == NBUK - 1) ? ETOT : bbase[k + 1];

    hist[t] = 0;
    hist[t + 256] = 0;
    __syncthreads();

    int v[MAXPER];
    #pragma unroll
    for (int j = 0; j < MAXPER; ++j) {
        const int idx = start + j * 256 + t;
        v[j] = (idx < end) ? esrc[idx] : -1;
    }
    #pragma unroll
    for (int j = 0; j < MAXPER; ++j)
        if (v[j] >= 0) atomicAdd(&hist[(v[j] >> 17) & 511], 1);
    __syncthreads();

    const int h0 = hist[2 * t], h1 = hist[2 * t + 1];
    const int pv = h0 + h1;
    const int l = t & 63, w = t >> 6;
    int inc = pv;
    #pragma unroll
    for (int off = 1; off < 64; off <<= 1) {
        int u = __shfl_up(inc, off);
        if (l >= off) inc += u;
    }
    if (l == 63) wt[w] = inc;
    __syncthreads();
    int add = 0;
    #pragma unroll
    for (int i = 0; i < 4; ++i) if (i < w) add += wt[i];
    const int ex = add + inc - pv;
    pre[2 * t] = ex;
    pre[2 * t + 1] = ex + h0;

    const int d0 = (k << BSH) + 2 * t;
    if (d0 < NN)     rowstart[d0]     = start + ex;
    if (d0 + 1 < NN) rowstart[d0 + 1] = start + ex + h0;
    __syncthreads();

    #pragma unroll
    for (int j = 0; j < MAXPER; ++j) {
        if (v[j] >= 0) {
            const int pos = atomicAdd(&pre[(v[j] >> 17) & 511], 1);
            esrc[start + pos] = v[j] & 0x1FFFF;
        }
    }
}

// ---------------------------------------------------------------------------
// K6: gather-aggregate (unchanged control; near its random-row-gather floor).
// ---------------------------------------------------------------------------
__global__ __launch_bounds__(256) void gather_kernel(
    const int* __restrict__ rowstart, const int* __restrict__ esrc,
    const float* __restrict__ asrc, const float* __restrict__ adst,
    const bf16* __restrict__ xh, const void* __restrict__ bias,
    const int* __restrict__ flag, void* __restrict__ out)
{
    const int d = blockIdx.x * 4 + (threadIdx.x >> 6);
    if (d >= NN) return;
    const int l = threadIdx.x & 63;
    const int h = l >> 3;
    const int isbf = *flag;

    const float ad = adst[d * HEADS + h];
    const int r0 = rowstart[d], r1 = rowstart[d + 1];
    const bf162* __restrict__ xrow = (const bf162*)xh;
    float a0 = 0.f, a1 = 0.f, ds = 0.f;

    int p = r0;
    for (; p + 8 <= r1; p += 8) {
        int s[8];
        #pragma unroll
        for (int j = 0; j < 8; ++j) s[j] = esrc[p + j];
        float v[8];
        #pragma unroll
        for (int j = 0; j < 8; ++j) v[j] = asrc[(unsigned)s[j] * HEADS + h];
        float2 xv[8];
        #pragma unroll
        for (int j = 0; j < 8; ++j)
            xv[j] = __bfloat1622float2(xrow[(unsigned)s[j] * 64u + (unsigned)l]);
        #pragma unroll
        for (int j = 0; j < 8; ++j) {
            float wj = __expf(lrelu(v[j] + ad));
            a0 += wj * xv[j].x;
            a1 += wj * xv[j].y;
            ds += wj;
        }
    }
    for (; p + 4 <= r1; p += 4) {
        int s0 = esrc[p + 0], s1 = esrc[p + 1], s2 = esrc[p + 2], s3 = esrc[p + 3];
        float v0 = asrc[(unsigned)s0 * HEADS + h];
        float v1 = asrc[(unsigned)s1 * HEADS + h];
        float v2 = asrc[(unsigned)s2 * HEADS + h];
        float v3 = asrc[(unsigned)s3 * HEADS + h];
        float2 x0 = __bfloat1622float2(xrow[(unsigned)s0 * 64u + (unsigned)l]);
        float2 x1 = __bfloat1622float2(xrow[(unsigned)s1 * 64u + (unsigned)l]);
        float2 x2 = __bfloat1622float2(xrow[(unsigned)s2 * 64u + (unsigned)l]);
        float2 x3 = __bfloat1622float2(xrow[(unsigned)s3 * 64u + (unsigned)l]);
        float w0 = __expf(lrelu(v0 + ad));
        float w1 = __expf(lrelu(v1 + ad));
        float w2 = __expf(lrelu(v2 + ad));
        float w3 = __expf(lrelu(v3 + ad));
        a0 += w0 * x0.x + w1 * x1.x + w2 * x2.x + w3 * x3.x;
        a1 += w0 * x0.y + w1 * x1.y + w2 * x2.y + w3 * x3.y;
        ds += (w0 + w1) + (w2 + w3);
    }
    for (; p < r1; ++p) {
        int s = esrc[p];
        float w = __expf(lrelu(asrc[(unsigned)s * HEADS + h] + ad));
        float2 xf = __bfloat1622float2(xrow[(unsigned)s * 64u + (unsigned)l]);
        a0 += w * xf.x;
        a1 += w * xf.y;
        ds += w;
    }

    float inv = 1.f / ds;
    float2 bf = load2(bias, l, isbf);
    float o0 = a0 * inv + bf.x;
    float o1 = a1 * inv + bf.y;
    if (isbf) {
        bf162 o;
        o.x = __float2bfloat16(o0);
        o.y = __float2bfloat16(o1);
        ((bf162*)out)[(size_t)d * 64 + l] = o;
    } else {
        ((float2*)out)[(size_t)d * 64 + l] = make_float2(o0, o1);
    }
}

extern "C" void kernel_launch(void* const* d_in, const int* in_sizes, int n_in,
                              void* d_out, int out_size, void* d_ws, size_t ws_size,
                              hipStream_t stream)
{
    const void* x     = d_in[0];
    const int*  ei    = (const int*)d_in[1];
    const void* W     = d_in[2];
    const void* bproj = d_in[3];
    const void* atts  = d_in[4];
    const void* attd  = d_in[5];
    const void* bias  = d_in[6];

    // workspace layout (~42 MB), all segments 16B-aligned
    char* p = (char*)d_ws;
    int*    flag     = (int*)p;    p += 16;
    bf16*   xh       = (bf16*)p;   p += (size_t)NN * DIM * sizeof(bf16);
    float*  asrc     = (float*)p;  p += (size_t)NN * HEADS * sizeof(float);
    float*  adst     = (float*)p;  p += (size_t)NN * HEADS * sizeof(float);
    int*    rowstart = (int*)p;    p += (size_t)(NN + 1) * sizeof(int) + 12;
    int*    esrc     = (int*)p;    p += (size_t)ETOT * sizeof(int);
    int*    cntmat   = (int*)p;    p += (size_t)NBUK * B1 * sizeof(int);
    int*    cntpre   = (int*)p;    p += (size_t)NBUK * B1 * sizeof(int);
    int*    btot     = (int*)p;    p += ((NBUK + 3) & ~3) * sizeof(int);
    int*    bbase    = (int*)p;    p += ((NBUK + 3) & ~3) * sizeof(int);

    proj_mfma_kernel<<<(NN + 63) / 64, 256, 0, stream>>>(x, W, bproj, atts, attd,
                                                         flag, xh, asrc, adst);

    {
        void* cargs[] = {(void*)&ei, (void*)&cntmat, (void*)&cntpre, (void*)&btot,
                         (void*)&bbase, (void*)&esrc, (void*)&rowstart};
        hipError_t cerr = hipLaunchCooperativeKernel(
            reinterpret_cast<void*>(csr_coop_kernel), dim3(B1), dim3(256),
            cargs, 0, stream);
        if (cerr != hipSuccess) {
            // fallback: round-5 five-kernel chain (identical math)
            csr_count_kernel<<<B1, 256, 0, stream>>>(ei, cntmat);
            csr_colscan_kernel<<<NBUK, 256, 0, stream>>>(cntmat, cntpre, btot);
            csr_base_kernel<<<1, 256, 0, stream>>>(btot, bbase, rowstart);
            csr_scatter_kernel<<<B1, 256, 0, stream>>>(ei, cntpre, bbase, esrc);
            csr_bucket_kernel<<<NBUK, 256, 0, stream>>>(bbase, esrc, rowstart);
        }
    }

    gather_kernel<<<(NN + 3) / 4, 256, 0, stream>>>(rowstart, esrc, asrc, adst,
                                                    xh, bias, flag, d_out);
}

// Round 7
// 274.938 us; speedup vs baseline: 2.4524x; 2.4524x over previous
//
#include <hip/hip_runtime.h>
#include <hip/hip_bf16.h>

typedef __hip_bfloat16 bf16;
typedef __hip_bfloat162 bf162;
typedef __attribute__((ext_vector_type(8))) short short8;   // 8 bf16 (4 VGPRs)
typedef __attribute__((ext_vector_type(4))) float f32x4;    // MFMA C/D

#define NN 100000
#define NE 1600000
#define ETOT (NE + NN)
#define DIM 128
#define HEADS 8

// ---- bucket-sort CSR build parameters ----
#define BSH 9                                   // bucket = dest >> 9 (512 dests)
#define NBUK ((NN + 511) >> BSH)                // 196
#define EPB 2048                                // edges per partition block
#define B1 ((ETOT + EPB - 1) / EPB)             // 831 blocks
#define MAXPER 40                               // regs/thread in bucket kernel
#define PROJ_BLKS ((NN + 63) / 64)              // 1563

__device__ __forceinline__ float lrelu(float v) { return v > 0.f ? v : 0.2f * v; }

__device__ __forceinline__ float load1(const void* p, int i, int isbf) {
    return isbf ? __bfloat162float(((const bf16*)p)[i]) : ((const float*)p)[i];
}
__device__ __forceinline__ float2 load2(const void* p, size_t pairIdx, int isbf) {
    if (isbf) return __bfloat1622float2(((const bf162*)p)[pairIdx]);
    return ((const float2*)p)[pairIdx];
}
__device__ __forceinline__ short f2bf(float f) {
    bf16 h = __float2bfloat16(f);
    return *reinterpret_cast<short*>(&h);
}

// ---------------------------------------------------------------------------
// K0: dtype detect + augmented weight rows (round-5 proven version).
// ---------------------------------------------------------------------------
__global__ __launch_bounds__(256) void aug_kernel(
    const void* __restrict__ W, const void* __restrict__ bproj,
    const void* __restrict__ atts, const void* __restrict__ attd,
    int* __restrict__ flag, bf16* __restrict__ waug, float* __restrict__ wc)
{
    __shared__ bf16 Wl[128 * 128];   // 32 KB
    __shared__ float av[256];        // atts | attd
    __shared__ float red[256];
    const int tid = threadIdx.x;

    // ---- detect ----
    {
        const bf16* wb = (const bf16*)W;
        float m = 0.f;
        for (int i = tid; i < 8192; i += 256) {
            float v = fabsf(__bfloat162float(wb[i]));
            if (!(v < 1e30f)) v = 1e30f;
            m = fmaxf(m, v);
        }
        red[tid] = m;
        __syncthreads();
        for (int s = 128; s > 0; s >>= 1) {
            if (tid < s) red[tid] = fmaxf(red[tid], red[tid + s]);
            __syncthreads();
        }
    }
    const int isbf = (red[0] < 1.0f) ? 1 : 0;
    if (tid == 0) *flag = isbf;

    // ---- aug ----
    for (int i = tid; i < 2048; i += 256) {       // 2048 chunks of 8 bf16
        short8 v;
        if (isbf) {
            v = ((const short8*)W)[i];
        } else {
            const float* wp = (const float*)W + (size_t)i * 8;
            #pragma unroll
            for (int j = 0; j < 8; ++j) v[j] = f2bf(wp[j]);
        }
        ((short8*)Wl)[i] = v;
    }
    av[tid & 255] = (tid < 128) ? load1(atts, tid, isbf)
                                : load1(attd, tid - 128, isbf);
    __syncthreads();

    #pragma unroll
    for (int it = 0; it < 8; ++it) {
        const int o = tid + it * 256;             // 0..2047
        const int row = o >> 7, col = o & 127;
        const int h = row & 7;
        const int ao = (row < 8) ? 0 : 128;
        float s = 0.f;
        #pragma unroll
        for (int t = 0; t < 16; ++t)
            s += av[ao + h * 16 + t] * __bfloat162float(Wl[(h * 16 + t) * 128 + col]);
        waug[o] = __float2bfloat16(s);
    }
    if (tid < 16) {
        const int h = tid & 7;
        const int ao = (tid < 8) ? 0 : 128;
        float s = 0.f;
        #pragma unroll
        for (int t = 0; t < 16; ++t)
            s += load1(bproj, h * 16 + t, isbf) * av[ao + h * 16 + t];
        wc[tid] = s;
    }
}

// ---------------------------------------------------------------------------
// K1: heterogeneous fused kernel.
//   blocks [0, PROJ_BLKS)          : MFMA projection (round-5 proven body)
//   blocks [PROJ_BLKS, +B1)        : CSR coarse-bucket count (round-5 body)
// The two halves touch disjoint data; fusing saves a launch drain and hides
// count's 6.8 MB edge stream under proj's compute.
// ---------------------------------------------------------------------------
__global__ __launch_bounds__(256) void projcount_kernel(
    const void* __restrict__ x, const void* __restrict__ W,
    const void* __restrict__ bproj, const bf16* __restrict__ waug,
    const float* __restrict__ wc, const int* __restrict__ flag,
    bf16* __restrict__ xh, float* __restrict__ asrc, float* __restrict__ adst,
    const int* __restrict__ ei, int* __restrict__ cntmat)
{
    __shared__ short8 Wf[2304];                 // 36 KB (proj) / count hist overlay
    __shared__ float bsh[DIM], csh[16];

    const int tid = threadIdx.x;

    // ===================== count half =====================
    if (blockIdx.x >= PROJ_BLKS) {
        const int b = blockIdx.x - PROJ_BLKS;
        int* cnt = (int*)Wf;
        for (int i = tid; i < NBUK; i += 256) cnt[i] = 0;
        __syncthreads();
        const int base = b * EPB;
        #pragma unroll
        for (int it = 0; it < EPB / 1024; ++it) {
            const int e = base + it * 1024 + tid * 4;   // ETOT%4==0, NE%4==0
            if (e < ETOT) {
                int4 d4;
                if (e < NE) {
                    d4 = *(const int4*)(ei + NE + e);
                } else {
                    d4.x = e - NE; d4.y = d4.x + 1; d4.z = d4.x + 2; d4.w = d4.x + 3;
                }
                atomicAdd(&cnt[d4.x >> BSH], 1);
                atomicAdd(&cnt[d4.y >> BSH], 1);
                atomicAdd(&cnt[d4.z >> BSH], 1);
                atomicAdd(&cnt[d4.w >> BSH], 1);
            }
        }
        __syncthreads();
        for (int k = tid; k < NBUK; k += 256) cntmat[k * B1 + b] = cnt[k];
        return;
    }

    // ===================== proj half (round-5 body) =====================
    const int isbf = *flag;

    for (int c = tid; c < 2048; c += 256) {
        int j = c >> 4, kc = c & 15;
        int kb = kc >> 2, quad = kc & 3;
        int lane = quad * 16 + (j & 15);
        int jt = j >> 4;
        short8 v;
        if (isbf) {
            v = ((const short8*)W)[c];          // 8 bf16 at W[j][kc*8]
        } else {
            const float* wp = (const float*)W + (size_t)j * DIM + kc * 8;
            #pragma unroll
            for (int i = 0; i < 8; ++i) v[i] = f2bf(wp[i]);
        }
        Wf[(jt * 4 + kb) * 64 + lane] = v;
    }
    {   // augmented tile (16 rows x 128 k), already bf16
        int c = tid;
        if (c < 256) {
            int j2 = c >> 4, kc = c & 15;
            int kb = kc >> 2, quad = kc & 3;
            Wf[(32 + kb) * 64 + quad * 16 + j2] = ((const short8*)waug)[c];
        }
    }
    if (tid < DIM) bsh[tid] = load1(bproj, tid, isbf);
    if (tid < 16)  csh[tid] = wc[tid];
    __syncthreads();

    const int w = tid >> 6;
    const int l = tid & 63;
    const int quad = l >> 4, mr = l & 15;
    const int n0 = blockIdx.x * 64 + w * 16;    // wave's first node
    const int nArd = min(n0 + mr, NN - 1);      // clamped A-frag row

    short8 afr[4];
    if (isbf) {
        const short8* xp = (const short8*)x + (size_t)nArd * 16;
        #pragma unroll
        for (int kb = 0; kb < 4; ++kb) afr[kb] = xp[kb * 4 + quad];
    } else {
        const float* xp = (const float*)x + (size_t)nArd * DIM;
        #pragma unroll
        for (int kb = 0; kb < 4; ++kb) {
            const float* cp = xp + kb * 32 + quad * 8;
            float4 c0 = *(const float4*)cp;
            float4 c1 = *(const float4*)(cp + 4);
            short8 v;
            v[0] = f2bf(c0.x); v[1] = f2bf(c0.y); v[2] = f2bf(c0.z); v[3] = f2bf(c0.w);
            v[4] = f2bf(c1.x); v[5] = f2bf(c1.y); v[6] = f2bf(c1.z); v[7] = f2bf(c1.w);
            afr[kb] = v;
        }
    }

    // ---- MFMA phase: keep all 8 xh-tiles in registers ----
    f32x4 accs[8];
    #pragma unroll
    for (int jt = 0; jt < 8; ++jt) {
        f32x4 acc = {0.f, 0.f, 0.f, 0.f};
        #pragma unroll
        for (int kb = 0; kb < 4; ++kb) {
            short8 b = Wf[(jt * 4 + kb) * 64 + l];
            acc = __builtin_amdgcn_mfma_f32_16x16x32_bf16(afr[kb], b, acc, 0, 0, 0);
        }
        accs[jt] = acc;
    }
    f32x4 acca = {0.f, 0.f, 0.f, 0.f};
    #pragma unroll
    for (int kb = 0; kb < 4; ++kb) {
        short8 b = Wf[(32 + kb) * 64 + l];
        acca = __builtin_amdgcn_mfma_f32_16x16x32_bf16(afr[kb], b, acca, 0, 0, 0);
    }

    __syncthreads();                            // all waves done reading Wf

    // ---- stage 16x128 bf16 tile in LDS (stride 136 elems = 272B) ----
    bf16* sw = ((bf16*)Wf) + w * (16 * 136);    // 4352 B per wave
    #pragma unroll
    for (int jt = 0; jt < 8; ++jt) {
        const int jj = jt * 16 + mr;
        const float bv = bsh[jj];
        #pragma unroll
        for (int r = 0; r < 4; ++r)
            sw[(quad * 4 + r) * 136 + jj] = __float2bfloat16(accs[jt][r] + bv);
    }
    // ---- coalesced write-back: 4 x short8 per lane ----
    #pragma unroll
    for (int g = 0; g < 4; ++g) {
        const int row = g * 4 + (l >> 4);       // 0..15
        const int n = n0 + row;
        if (n < NN)
            *((short8*)(xh + (size_t)n * DIM) + (l & 15)) =
                *(const short8*)(sw + row * 136 + (l & 15) * 8);
    }

    // ---- asrc/adst from the augmented tile ----
    {
        const float cst = csh[mr];
        #pragma unroll
        for (int r = 0; r < 4; ++r) {
            const int n = n0 + quad * 4 + r;
            if (n < NN) {
                float v = acca[r] + cst;
                if (mr < 8) asrc[n * HEADS + mr] = v;
                else        adst[n * HEADS + (mr - 8)] = v;
            }
        }
    }
}

// ---------------------------------------------------------------------------
// CSR pass 1b: per-bucket exclusive scan over B1 block counts (round-5).
// ---------------------------------------------------------------------------
__global__ __launch_bounds__(256) void csr_colscan_kernel(const int* __restrict__ cntmat,
                                                          int* __restrict__ cntpre,
                                                          int* __restrict__ btot)
{
    const int k = blockIdx.x, t = threadIdx.x;
    int v[4];
    int s = 0;
    #pragma unroll
    for (int j = 0; j < 4; ++j) {
        const int c = t * 4 + j;
        v[j] = (c < B1) ? cntmat[k * B1 + c] : 0;
        s += v[j];
    }
    const int l = t & 63, w = t >> 6;
    int inc = s;
    #pragma unroll
    for (int off = 1; off < 64; off <<= 1) {
        int u = __shfl_up(inc, off);
        if (l >= off) inc += u;
    }
    __shared__ int wt[4];
    if (l == 63) wt[w] = inc;
    __syncthreads();
    int add = 0;
    #pragma unroll
    for (int i = 0; i < 4; ++i) if (i < w) add += wt[i];
    int run = add + inc - s;
    #pragma unroll
    for (int j = 0; j < 4; ++j) {
        const int c = t * 4 + j;
        if (c < B1) cntpre[k * B1 + c] = run;
        run += v[j];
    }
    if (t == 255) btot[k] = add + inc;
}

// ---------------------------------------------------------------------------
// In-block exclusive scan of btot[NBUK] -> bb[] (LDS).  Replaces the
// dedicated csr_base launch; each block recomputes it in ~1 us.
// ---------------------------------------------------------------------------
__device__ __forceinline__ void scan_btot(const int* __restrict__ btot,
                                          int* __restrict__ bb, int* __restrict__ wt4)
{
    const int t = threadIdx.x;
    const int v = (t < NBUK) ? btot[t] : 0;
    const int l = t & 63, w = t >> 6;
    int inc = v;
    #pragma unroll
    for (int off = 1; off < 64; off <<= 1) {
        int u = __shfl_up(inc, off);
        if (l >= off) inc += u;
    }
    if (l == 63) wt4[w] = inc;
    __syncthreads();
    int add = 0;
    #pragma unroll
    for (int i = 0; i < 4; ++i) if (i < w) add += wt4[i];
    if (t < NBUK) bb[t] = add + inc - v;
    __syncthreads();
}

// ---------------------------------------------------------------------------
// CSR pass 2: bucket-grouped scatter (round-5 body, base scan folded in).
// ---------------------------------------------------------------------------
__global__ __launch_bounds__(256) void csr_scatter_kernel(const int* __restrict__ ei,
                                                          const int* __restrict__ cntpre,
                                                          const int* __restrict__ btot,
                                                          int* __restrict__ esrc)
{
    __shared__ int cur[NBUK];
    __shared__ int bb[NBUK];
    __shared__ int wt4[4];
    const int t = threadIdx.x, b = blockIdx.x;

    scan_btot(btot, bb, wt4);
    for (int k = t; k < NBUK; k += 256) cur[k] = bb[k] + cntpre[k * B1 + b];
    __syncthreads();

    const int base = b * EPB;
    #pragma unroll
    for (int it = 0; it < EPB / 1024; ++it) {
        const int e = base + it * 1024 + t * 4;
        if (e < ETOT) {
            int4 d4, s4;
            if (e < NE) {
                s4 = *(const int4*)(ei + e);
                d4 = *(const int4*)(ei + NE + e);
            } else {
                s4.x = e - NE; s4.y = s4.x + 1; s4.z = s4.x + 2; s4.w = s4.x + 3;
                d4 = s4;
            }
            const int p0 = atomicAdd(&cur[d4.x >> BSH], 1);
            const int p1 = atomicAdd(&cur[d4.y >> BSH], 1);
            const int p2 = atomicAdd(&cur[d4.z >> BSH], 1);
            const int p3 = atomicAdd(&cur[d4.w >> BSH], 1);
            esrc[p0] = s4.x | ((d4.x & 511) << 17);
            esrc[p1] = s4.y | ((d4.y & 511) << 17);
            esrc[p2] = s4.z | ((d4.z & 511) << 17);
            esrc[p3] = s4.w | ((d4.w & 511) << 17);
        }
    }
}

// ---------------------------------------------------------------------------
// CSR pass 3: in-bucket sort + rowstart write (round-5 body, base folded).
// ---------------------------------------------------------------------------
__global__ __launch_bounds__(256) void csr_bucket_kernel(const int* __restrict__ btot,
                                                         int* __restrict__ esrc,
                                                         int* __restrict__ rowstart)
{
    __shared__ int hist[512];
    __shared__ int pre[512];
    __shared__ int bb[NBUK];
    __shared__ int wt4[4];
    const int k = blockIdx.x, t = threadIdx.x;

    scan_btot(btot, bb, wt4);
    const int start = bb[k];
    const int end = start + btot[k];
    if (k == 0 && t == 0) rowstart[NN] = ETOT;

    hist[t] = 0;
    hist[t + 256] = 0;
    __syncthreads();

    // load bucket to registers (statically indexed -> stays in VGPRs)
    int v[MAXPER];
    #pragma unroll
    for (int j = 0; j < MAXPER; ++j) {
        const int idx = start + j * 256 + t;
        v[j] = (idx < end) ? esrc[idx] : -1;
    }
    #pragma unroll
    for (int j = 0; j < MAXPER; ++j)
        if (v[j] >= 0) atomicAdd(&hist[(v[j] >> 17) & 511], 1);
    __syncthreads();

    // exclusive scan of 512 dest counts (pairs per thread)
    const int h0 = hist[2 * t], h1 = hist[2 * t + 1];
    const int pv = h0 + h1;
    const int l = t & 63, w = t >> 6;
    int inc = pv;
    #pragma unroll
    for (int off = 1; off < 64; off <<= 1) {
        int u = __shfl_up(inc, off);
        if (l >= off) inc += u;
    }
    if (l == 63) wt4[w] = inc;
    __syncthreads();
    int add = 0;
    #pragma unroll
    for (int i = 0; i < 4; ++i) if (i < w) add += wt4[i];
    const int ex = add + inc - pv;
    pre[2 * t] = ex;
    pre[2 * t + 1] = ex + h0;

    // rowstart for this bucket's dest range
    const int d0 = (k << BSH) + 2 * t;
    if (d0 < NN)     rowstart[d0]     = start + ex;
    if (d0 + 1 < NN) rowstart[d0 + 1] = start + ex + h0;
    __syncthreads();

    // in-place scatter: plain src (block owns [start,end) exclusively)
    #pragma unroll
    for (int j = 0; j < MAXPER; ++j) {
        if (v[j] >= 0) {
            const int pos = atomicAdd(&pre[(v[j] >> 17) & 511], 1);
            esrc[start + pos] = v[j] & 0x1FFFF;
        }
    }
}

// ---------------------------------------------------------------------------
// K6: gather-aggregate (unchanged control; near its random-row-gather floor).
// ---------------------------------------------------------------------------
__global__ __launch_bounds__(256) void gather_kernel(
    const int* __restrict__ rowstart, const int* __restrict__ esrc,
    const float* __restrict__ asrc, const float* __restrict__ adst,
    const bf16* __restrict__ xh, const void* __restrict__ bias,
    const int* __restrict__ flag, void* __restrict__ out)
{
    const int d = blockIdx.x * 4 + (threadIdx.x >> 6);
    if (d >= NN) return;
    const int l = threadIdx.x & 63;
    const int h = l >> 3;
    const int isbf = *flag;

    const float ad = adst[d * HEADS + h];
    const int r0 = rowstart[d], r1 = rowstart[d + 1];
    const bf162* __restrict__ xrow = (const bf162*)xh;
    float a0 = 0.f, a1 = 0.f, ds = 0.f;

    int p = r0;
    for (; p + 8 <= r1; p += 8) {
        int s[8];
        #pragma unroll
        for (int j = 0; j < 8; ++j) s[j] = esrc[p + j];
        float v[8];
        #pragma unroll
        for (int j = 0; j < 8; ++j) v[j] = asrc[(unsigned)s[j] * HEADS + h];
        float2 xv[8];
        #pragma unroll
        for (int j = 0; j < 8; ++j)
            xv[j] = __bfloat1622float2(xrow[(unsigned)s[j] * 64u + (unsigned)l]);
        #pragma unroll
        for (int j = 0; j < 8; ++j) {
            float wj = __expf(lrelu(v[j] + ad));
            a0 += wj * xv[j].x;
            a1 += wj * xv[j].y;
            ds += wj;
        }
    }
    for (; p + 4 <= r1; p += 4) {
        int s0 = esrc[p + 0], s1 = esrc[p + 1], s2 = esrc[p + 2], s3 = esrc[p + 3];
        float v0 = asrc[(unsigned)s0 * HEADS + h];
        float v1 = asrc[(unsigned)s1 * HEADS + h];
        float v2 = asrc[(unsigned)s2 * HEADS + h];
        float v3 = asrc[(unsigned)s3 * HEADS + h];
        float2 x0 = __bfloat1622float2(xrow[(unsigned)s0 * 64u + (unsigned)l]);
        float2 x1 = __bfloat1622float2(xrow[(unsigned)s1 * 64u + (unsigned)l]);
        float2 x2 = __bfloat1622float2(xrow[(unsigned)s2 * 64u + (unsigned)l]);
        float2 x3 = __bfloat1622float2(xrow[(unsigned)s3 * 64u + (unsigned)l]);
        float w0 = __expf(lrelu(v0 + ad));
        float w1 = __expf(lrelu(v1 + ad));
        float w2 = __expf(lrelu(v2 + ad));
        float w3 = __expf(lrelu(v3 + ad));
        a0 += w0 * x0.x + w1 * x1.x + w2 * x2.x + w3 * x3.x;
        a1 += w0 * x0.y + w1 * x1.y + w2 * x2.y + w3 * x3.y;
        ds += (w0 + w1) + (w2 + w3);
    }
    for (; p < r1; ++p) {
        int s = esrc[p];
        float w = __expf(lrelu(asrc[(unsigned)s * HEADS + h] + ad));
        float2 xf = __bfloat1622float2(xrow[(unsigned)s * 64u + (unsigned)l]);
        a0 += w * xf.x;
        a1 += w * xf.y;
        ds += w;
    }

    float inv = 1.f / ds;
    float2 bf = load2(bias, l, isbf);
    float o0 = a0 * inv + bf.x;
    float o1 = a1 * inv + bf.y;
    if (isbf) {
        bf162 o;
        o.x = __float2bfloat16(o0);
        o.y = __float2bfloat16(o1);
        ((bf162*)out)[(size_t)d * 64 + l] = o;
    } else {
        ((float2*)out)[(size_t)d * 64 + l] = make_float2(o0, o1);
    }
}

extern "C" void kernel_launch(void* const* d_in, const int* in_sizes, int n_in,
                              void* d_out, int out_size, void* d_ws, size_t ws_size,
                              hipStream_t stream)
{
    const void* x     = d_in[0];
    const int*  ei    = (const int*)d_in[1];
    const void* W     = d_in[2];
    const void* bproj = d_in[3];
    const void* atts  = d_in[4];
    const void* attd  = d_in[5];
    const void* bias  = d_in[6];

    // workspace layout (~42 MB), all segments 16B-aligned
    char* p = (char*)d_ws;
    int*    flag     = (int*)p;    p += 16;
    bf16*   xh       = (bf16*)p;   p += (size_t)NN * DIM * sizeof(bf16);
    float*  asrc     = (float*)p;  p += (size_t)NN * HEADS * sizeof(float);
    float*  adst     = (float*)p;  p += (size_t)NN * HEADS * sizeof(float);
    int*    rowstart = (int*)p;    p += (size_t)(NN + 1) * sizeof(int) + 12;
    int*    esrc     = (int*)p;    p += (size_t)ETOT * sizeof(int);
    int*    cntmat   = (int*)p;    p += (size_t)NBUK * B1 * sizeof(int);
    int*    cntpre   = (int*)p;    p += (size_t)NBUK * B1 * sizeof(int);
    int*    btot     = (int*)p;    p += ((NBUK + 3) & ~3) * sizeof(int);
    bf16*   waug     = (bf16*)p;   p += 16 * 128 * sizeof(bf16);
    float*  wc       = (float*)p;  p += 16 * sizeof(float);

    aug_kernel<<<1, 256, 0, stream>>>(W, bproj, atts, attd, flag, waug, wc);
    projcount_kernel<<<PROJ_BLKS + B1, 256, 0, stream>>>(x, W, bproj, waug, wc,
                                                         flag, xh, asrc, adst,
                                                         ei, cntmat);
    csr_colscan_kernel<<<NBUK, 256, 0, stream>>>(cntmat, cntpre, btot);
    csr_scatter_kernel<<<B1, 256, 0, stream>>>(ei, cntpre, btot, esrc);
    csr_bucket_kernel<<<NBUK, 256, 0, stream>>>(btot, esrc, rowstart);
    gather_kernel<<<(NN + 3) / 4, 256, 0, stream>>>(rowstart, esrc, asrc, adst,
                                                    xh, bias, flag, d_out);
}

// Round 8
// 273.750 us; speedup vs baseline: 2.4630x; 1.0043x over previous
//
#include <hip/hip_runtime.h>
#include <hip/hip_bf16.h>

typedef __hip_bfloat16 bf16;
typedef __hip_bfloat162 bf162;
typedef __attribute__((ext_vector_type(8))) short short8;   // 8 bf16 (4 VGPRs)
typedef __attribute__((ext_vector_type(4))) float f32x4;    // MFMA C/D

#define NN 100000
#define NE 1600000
#define ETOT (NE + NN)
#define DIM 128
#define HEADS 8

// ---- bucket-sort CSR build parameters ----
#define BSH 9                                   // bucket = dest >> 9 (512 dests)
#define NBUK ((NN + 511) >> BSH)                // 196
#define EPB 2048                                // edges per scatter block
#define B1 ((ETOT + EPB - 1) / EPB)             // 831 scatter blocks
#define EPB2 8192                               // edges per count block
#define B2 ((ETOT + EPB2 - 1) / EPB2)           // 208 count blocks
#define MAXPER 40                               // regs/thread in bucket kernel
#define PROJ_BLKS ((NN + 63) / 64)              // 1563

__device__ __forceinline__ float lrelu(float v) { return v > 0.f ? v : 0.2f * v; }

__device__ __forceinline__ float load1(const void* p, int i, int isbf) {
    return isbf ? __bfloat162float(((const bf16*)p)[i]) : ((const float*)p)[i];
}
__device__ __forceinline__ float2 load2(const void* p, size_t pairIdx, int isbf) {
    if (isbf) return __bfloat1622float2(((const bf162*)p)[pairIdx]);
    return ((const float2*)p)[pairIdx];
}
__device__ __forceinline__ short f2bf(float f) {
    bf16 h = __float2bfloat16(f);
    return *reinterpret_cast<short*>(&h);
}

// exclusive scan of btot[NBUK] -> bb[] in LDS (one 256-thread block)
__device__ __forceinline__ void scan_btot(const int* __restrict__ btot,
                                          int* __restrict__ bb, int* __restrict__ wt4)
{
    const int t = threadIdx.x;
    const int v = (t < NBUK) ? btot[t] : 0;
    const int l = t & 63, w = t >> 6;
    int inc = v;
    #pragma unroll
    for (int off = 1; off < 64; off <<= 1) {
        int u = __shfl_up(inc, off);
        if (l >= off) inc += u;
    }
    if (l == 63) wt4[w] = inc;
    __syncthreads();
    int add = 0;
    #pragma unroll
    for (int i = 0; i < 4; ++i) if (i < w) add += wt4[i];
    if (t < NBUK) bb[t] = add + inc - v;
    __syncthreads();
}

// ---------------------------------------------------------------------------
// K1 (launch 2): heterogeneous {count || aug}.
//   blocks [0, B2)  : coarse-bucket count, LDS hist -> 196 global atomicAdds
//   block  B2       : dtype detect + augmented weight rows (round-5 proven)
// btot/gcur are zeroed by the preceding hipMemsetAsync.
// ---------------------------------------------------------------------------
__global__ __launch_bounds__(256) void aug_count_kernel(
    const void* __restrict__ W, const void* __restrict__ bproj,
    const void* __restrict__ atts, const void* __restrict__ attd,
    int* __restrict__ flag, bf16* __restrict__ waug, float* __restrict__ wc,
    const int* __restrict__ ei, int* __restrict__ btot)
{
    __shared__ char smem[32768 + 2048];
    const int tid = threadIdx.x;

    if (blockIdx.x < B2) {
        // ===================== count half =====================
        int* cnt = (int*)smem;
        for (int i = tid; i < NBUK; i += 256) cnt[i] = 0;
        __syncthreads();
        const int base = blockIdx.x * EPB2;
        #pragma unroll
        for (int it = 0; it < EPB2 / 1024; ++it) {
            const int e = base + it * 1024 + tid * 4;   // ETOT%4==0, NE%4==0
            if (e < ETOT) {
                int4 d4;
                if (e < NE) {
                    d4 = *(const int4*)(ei + NE + e);
                } else {
                    d4.x = e - NE; d4.y = d4.x + 1; d4.z = d4.x + 2; d4.w = d4.x + 3;
                }
                atomicAdd(&cnt[d4.x >> BSH], 1);
                atomicAdd(&cnt[d4.y >> BSH], 1);
                atomicAdd(&cnt[d4.z >> BSH], 1);
                atomicAdd(&cnt[d4.w >> BSH], 1);
            }
        }
        __syncthreads();
        for (int k = tid; k < NBUK; k += 256) {
            const int c = cnt[k];
            if (c) atomicAdd(&btot[k], c);
        }
        return;
    }

    // ===================== aug half (block B2) =====================
    bf16*  Wl  = (bf16*)smem;                 // 32 KB
    float* av  = (float*)(smem + 32768);      // 1 KB: atts | attd
    float* red = av + 256;                    // 1 KB

    // ---- detect ----
    {
        const bf16* wb = (const bf16*)W;
        float m = 0.f;
        for (int i = tid; i < 8192; i += 256) {
            float v = fabsf(__bfloat162float(wb[i]));
            if (!(v < 1e30f)) v = 1e30f;
            m = fmaxf(m, v);
        }
        red[tid] = m;
        __syncthreads();
        for (int s = 128; s > 0; s >>= 1) {
            if (tid < s) red[tid] = fmaxf(red[tid], red[tid + s]);
            __syncthreads();
        }
    }
    const int isbf = (red[0] < 1.0f) ? 1 : 0;
    if (tid == 0) *flag = isbf;

    // ---- aug ----
    for (int i = tid; i < 2048; i += 256) {       // 2048 chunks of 8 bf16
        short8 v;
        if (isbf) {
            v = ((const short8*)W)[i];
        } else {
            const float* wp = (const float*)W + (size_t)i * 8;
            #pragma unroll
            for (int j = 0; j < 8; ++j) v[j] = f2bf(wp[j]);
        }
        ((short8*)Wl)[i] = v;
    }
    av[tid & 255] = (tid < 128) ? load1(atts, tid, isbf)
                                : load1(attd, tid - 128, isbf);
    __syncthreads();

    #pragma unroll
    for (int it = 0; it < 8; ++it) {
        const int o = tid + it * 256;             // 0..2047
        const int row = o >> 7, col = o & 127;
        const int h = row & 7;
        const int ao = (row < 8) ? 0 : 128;
        float s = 0.f;
        #pragma unroll
        for (int t = 0; t < 16; ++t)
            s += av[ao + h * 16 + t] * __bfloat162float(Wl[(h * 16 + t) * 128 + col]);
        waug[o] = __float2bfloat16(s);
    }
    if (tid < 16) {
        const int h = tid & 7;
        const int ao = (tid < 8) ? 0 : 128;
        float s = 0.f;
        #pragma unroll
        for (int t = 0; t < 16; ++t)
            s += load1(bproj, h * 16 + t, isbf) * av[ao + h * 16 + t];
        wc[tid] = s;
    }
}

// ---------------------------------------------------------------------------
// K2 (launch 3): heterogeneous {proj || scatter}.
//   blocks [0, PROJ_BLKS)       : MFMA projection (round-5/7 proven body)
//   blocks [PROJ_BLKS, +B1)     : chunk-reservation scatter: self-histogram
//     2048 edges, reserve a contiguous slot range per bucket via ONE global
//     atomicAdd(&gcur[k], c), then LDS-cursor write of packed edges.
//     Replaces colscan + cntmat/cntpre entirely.
// ---------------------------------------------------------------------------
__global__ __launch_bounds__(256) void proj_scatter_kernel(
    const void* __restrict__ x, const void* __restrict__ W,
    const void* __restrict__ bproj, const bf16* __restrict__ waug,
    const float* __restrict__ wc, const int* __restrict__ flag,
    bf16* __restrict__ xh, float* __restrict__ asrc, float* __restrict__ adst,
    const int* __restrict__ ei, const int* __restrict__ btot,
    int* __restrict__ gcur, int* __restrict__ esrc)
{
    __shared__ short8 Wf[2304];                 // 36 KB (proj) / scatter overlay
    __shared__ float bsh[DIM], csh[16];

    const int tid = threadIdx.x;

    if (blockIdx.x >= PROJ_BLKS) {
        // ===================== scatter half =====================
        int* hist = (int*)Wf;                   // [NBUK]
        int* cur  = hist + NBUK;                // [NBUK]
        int* bb   = cur + NBUK;                 // [NBUK]
        int* wt4  = bb + NBUK;                  // [4]
        const int b = blockIdx.x - PROJ_BLKS;

        for (int i = tid; i < NBUK; i += 256) hist[i] = 0;
        __syncthreads();

        const int base = b * EPB;
        int4 s4[2], d4[2];
        int valid[2];
        #pragma unroll
        for (int it = 0; it < 2; ++it) {
            const int e = base + it * 1024 + tid * 4;
            valid[it] = (e < ETOT);
            if (valid[it]) {
                if (e < NE) {
                    s4[it] = *(const int4*)(ei + e);
                    d4[it] = *(const int4*)(ei + NE + e);
                } else {
                    s4[it].x = e - NE; s4[it].y = s4[it].x + 1;
                    s4[it].z = s4[it].x + 2; s4[it].w = s4[it].x + 3;
                    d4[it] = s4[it];
                }
                atomicAdd(&hist[d4[it].x >> BSH], 1);
                atomicAdd(&hist[d4[it].y >> BSH], 1);
                atomicAdd(&hist[d4[it].z >> BSH], 1);
                atomicAdd(&hist[d4[it].w >> BSH], 1);
            }
        }
        __syncthreads();

        scan_btot(btot, bb, wt4);               // bb = bucket global bases

        // reserve a contiguous chunk per bucket with edges in this block
        for (int k = tid; k < NBUK; k += 256) {
            const int c = hist[k];
            cur[k] = c ? (bb[k] + atomicAdd(&gcur[k], c)) : 0;
        }
        __syncthreads();

        #pragma unroll
        for (int it = 0; it < 2; ++it) {
            if (valid[it]) {
                const int p0 = atomicAdd(&cur[d4[it].x >> BSH], 1);
                const int p1 = atomicAdd(&cur[d4[it].y >> BSH], 1);
                const int p2 = atomicAdd(&cur[d4[it].z >> BSH], 1);
                const int p3 = atomicAdd(&cur[d4[it].w >> BSH], 1);
                esrc[p0] = s4[it].x | ((d4[it].x & 511) << 17);
                esrc[p1] = s4[it].y | ((d4[it].y & 511) << 17);
                esrc[p2] = s4[it].z | ((d4[it].z & 511) << 17);
                esrc[p3] = s4[it].w | ((d4[it].w & 511) << 17);
            }
        }
        return;
    }

    // ===================== proj half (round-7 proven body) =====================
    const int isbf = *flag;

    for (int c = tid; c < 2048; c += 256) {
        int j = c >> 4, kc = c & 15;
        int kb = kc >> 2, quad = kc & 3;
        int lane = quad * 16 + (j & 15);
        int jt = j >> 4;
        short8 v;
        if (isbf) {
            v = ((const short8*)W)[c];          // 8 bf16 at W[j][kc*8]
        } else {
            const float* wp = (const float*)W + (size_t)j * DIM + kc * 8;
            #pragma unroll
            for (int i = 0; i < 8; ++i) v[i] = f2bf(wp[i]);
        }
        Wf[(jt * 4 + kb) * 64 + lane] = v;
    }
    {   // augmented tile (16 rows x 128 k), already bf16
        int c = tid;
        if (c < 256) {
            int j2 = c >> 4, kc = c & 15;
            int kb = kc >> 2, quad = kc & 3;
            Wf[(32 + kb) * 64 + quad * 16 + j2] = ((const short8*)waug)[c];
        }
    }
    if (tid < DIM) bsh[tid] = load1(bproj, tid, isbf);
    if (tid < 16)  csh[tid] = wc[tid];
    __syncthreads();

    const int w = tid >> 6;
    const int l = tid & 63;
    const int quad = l >> 4, mr = l & 15;
    const int n0 = blockIdx.x * 64 + w * 16;    // wave's first node
    const int nArd = min(n0 + mr, NN - 1);      // clamped A-frag row

    short8 afr[4];
    if (isbf) {
        const short8* xp = (const short8*)x + (size_t)nArd * 16;
        #pragma unroll
        for (int kb = 0; kb < 4; ++kb) afr[kb] = xp[kb * 4 + quad];
    } else {
        const float* xp = (const float*)x + (size_t)nArd * DIM;
        #pragma unroll
        for (int kb = 0; kb < 4; ++kb) {
            const float* cp = xp + kb * 32 + quad * 8;
            float4 c0 = *(const float4*)cp;
            float4 c1 = *(const float4*)(cp + 4);
            short8 v;
            v[0] = f2bf(c0.x); v[1] = f2bf(c0.y); v[2] = f2bf(c0.z); v[3] = f2bf(c0.w);
            v[4] = f2bf(c1.x); v[5] = f2bf(c1.y); v[6] = f2bf(c1.z); v[7] = f2bf(c1.w);
            afr[kb] = v;
        }
    }

    // ---- MFMA phase: keep all 8 xh-tiles in registers ----
    f32x4 accs[8];
    #pragma unroll
    for (int jt = 0; jt < 8; ++jt) {
        f32x4 acc = {0.f, 0.f, 0.f, 0.f};
        #pragma unroll
        for (int kb = 0; kb < 4; ++kb) {
            short8 b = Wf[(jt * 4 + kb) * 64 + l];
            acc = __builtin_amdgcn_mfma_f32_16x16x32_bf16(afr[kb], b, acc, 0, 0, 0);
        }
        accs[jt] = acc;
    }
    f32x4 acca = {0.f, 0.f, 0.f, 0.f};
    #pragma unroll
    for (int kb = 0; kb < 4; ++kb) {
        short8 b = Wf[(32 + kb) * 64 + l];
        acca = __builtin_amdgcn_mfma_f32_16x16x32_bf16(afr[kb], b, acca, 0, 0, 0);
    }

    __syncthreads();                            // all waves done reading Wf

    // ---- stage 16x128 bf16 tile in LDS (stride 136 elems = 272B) ----
    bf16* sw = ((bf16*)Wf) + w * (16 * 136);    // 4352 B per wave
    #pragma unroll
    for (int jt = 0; jt < 8; ++jt) {
        const int jj = jt * 16 + mr;
        const float bv = bsh[jj];
        #pragma unroll
        for (int r = 0; r < 4; ++r)
            sw[(quad * 4 + r) * 136 + jj] = __float2bfloat16(accs[jt][r] + bv);
    }
    // ---- coalesced write-back: 4 x short8 per lane ----
    #pragma unroll
    for (int g = 0; g < 4; ++g) {
        const int row = g * 4 + (l >> 4);       // 0..15
        const int n = n0 + row;
        if (n < NN)
            *((short8*)(xh + (size_t)n * DIM) + (l & 15)) =
                *(const short8*)(sw + row * 136 + (l & 15) * 8);
    }

    // ---- asrc/adst from the augmented tile ----
    {
        const float cst = csh[mr];
        #pragma unroll
        for (int r = 0; r < 4; ++r) {
            const int n = n0 + quad * 4 + r;
            if (n < NN) {
                float v = acca[r] + cst;
                if (mr < 8) asrc[n * HEADS + mr] = v;
                else        adst[n * HEADS + (mr - 8)] = v;
            }
        }
    }
}

// ---------------------------------------------------------------------------
// K3 (launch 4): in-bucket sort + rowstart write (round-7 proven body).
// ---------------------------------------------------------------------------
__global__ __launch_bounds__(256) void csr_bucket_kernel(const int* __restrict__ btot,
                                                         int* __restrict__ esrc,
                                                         int* __restrict__ rowstart)
{
    __shared__ int hist[512];
    __shared__ int pre[512];
    __shared__ int bb[NBUK];
    __shared__ int wt4[4];
    const int k = blockIdx.x, t = threadIdx.x;

    scan_btot(btot, bb, wt4);
    const int start = bb[k];
    const int end = start + btot[k];
    if (k == 0 && t == 0) rowstart[NN] = ETOT;

    hist[t] = 0;
    hist[t + 256] = 0;
    __syncthreads();

    // load bucket to registers (statically indexed -> stays in VGPRs)
    int v[MAXPER];
    #pragma unroll
    for (int j = 0; j < MAXPER; ++j) {
        const int idx = start + j * 256 + t;
        v[j] = (idx < end) ? esrc[idx] : -1;
    }
    #pragma unroll
    for (int j = 0; j < MAXPER; ++j)
        if (v[j] >= 0) atomicAdd(&hist[(v[j] >> 17) & 511], 1);
    __syncthreads();

    // exclusive scan of 512 dest counts (pairs per thread)
    const int h0 = hist[2 * t], h1 = hist[2 * t + 1];
    const int pv = h0 + h1;
    const int l = t & 63, w = t >> 6;
    int inc = pv;
    #pragma unroll
    for (int off = 1; off < 64; off <<= 1) {
        int u = __shfl_up(inc, off);
        if (l >= off) inc += u;
    }
    if (l == 63) wt4[w] = inc;
    __syncthreads();
    int add = 0;
    #pragma unroll
    for (int i = 0; i < 4; ++i) if (i < w) add += wt4[i];
    const int ex = add + inc - pv;
    pre[2 * t] = ex;
    pre[2 * t + 1] = ex + h0;

    // rowstart for this bucket's dest range
    const int d0 = (k << BSH) + 2 * t;
    if (d0 < NN)     rowstart[d0]     = start + ex;
    if (d0 + 1 < NN) rowstart[d0 + 1] = start + ex + h0;
    __syncthreads();

    // in-place scatter: plain src (block owns [start,end) exclusively)
    #pragma unroll
    for (int j = 0; j < MAXPER; ++j) {
        if (v[j] >= 0) {
            const int pos = atomicAdd(&pre[(v[j] >> 17) & 511], 1);
            esrc[start + pos] = v[j] & 0x1FFFF;
        }
    }
}

// ---------------------------------------------------------------------------
// K4 (launch 5): gather-aggregate (unchanged control).
// ---------------------------------------------------------------------------
__global__ __launch_bounds__(256) void gather_kernel(
    const int* __restrict__ rowstart, const int* __restrict__ esrc,
    const float* __restrict__ asrc, const float* __restrict__ adst,
    const bf16* __restrict__ xh, const void* __restrict__ bias,
    const int* __restrict__ flag, void* __restrict__ out)
{
    const int d = blockIdx.x * 4 + (threadIdx.x >> 6);
    if (d >= NN) return;
    const int l = threadIdx.x & 63;
    const int h = l >> 3;
    const int isbf = *flag;

    const float ad = adst[d * HEADS + h];
    const int r0 = rowstart[d], r1 = rowstart[d + 1];
    const bf162* __restrict__ xrow = (const bf162*)xh;
    float a0 = 0.f, a1 = 0.f, ds = 0.f;

    int p = r0;
    for (; p + 8 <= r1; p += 8) {
        int s[8];
        #pragma unroll
        for (int j = 0; j < 8; ++j) s[j] = esrc[p + j];
        float v[8];
        #pragma unroll
        for (int j = 0; j < 8; ++j) v[j] = asrc[(unsigned)s[j] * HEADS + h];
        float2 xv[8];
        #pragma unroll
        for (int j = 0; j < 8; ++j)
            xv[j] = __bfloat1622float2(xrow[(unsigned)s[j] * 64u + (unsigned)l]);
        #pragma unroll
        for (int j = 0; j < 8; ++j) {
            float wj = __expf(lrelu(v[j] + ad));
            a0 += wj * xv[j].x;
            a1 += wj * xv[j].y;
            ds += wj;
        }
    }
    for (; p + 4 <= r1; p += 4) {
        int s0 = esrc[p + 0], s1 = esrc[p + 1], s2 = esrc[p + 2], s3 = esrc[p + 3];
        float v0 = asrc[(unsigned)s0 * HEADS + h];
        float v1 = asrc[(unsigned)s1 * HEADS + h];
        float v2 = asrc[(unsigned)s2 * HEADS + h];
        float v3 = asrc[(unsigned)s3 * HEADS + h];
        float2 x0 = __bfloat1622float2(xrow[(unsigned)s0 * 64u + (unsigned)l]);
        float2 x1 = __bfloat1622float2(xrow[(unsigned)s1 * 64u + (unsigned)l]);
        float2 x2 = __bfloat1622float2(xrow[(unsigned)s2 * 64u + (unsigned)l]);
        float2 x3 = __bfloat1622float2(xrow[(unsigned)s3 * 64u + (unsigned)l]);
        float w0 = __expf(lrelu(v0 + ad));
        float w1 = __expf(lrelu(v1 + ad));
        float w2 = __expf(lrelu(v2 + ad));
        float w3 = __expf(lrelu(v3 + ad));
        a0 += w0 * x0.x + w1 * x1.x + w2 * x2.x + w3 * x3.x;
        a1 += w0 * x0.y + w1 * x1.y + w2 * x2.y + w3 * x3.y;
        ds += (w0 + w1) + (w2 + w3);
    }
    for (; p < r1; ++p) {
        int s = esrc[p];
        float w = __expf(lrelu(asrc[(unsigned)s * HEADS + h] + ad));
        float2 xf = __bfloat1622float2(xrow[(unsigned)s * 64u + (unsigned)l]);
        a0 += w * xf.x;
        a1 += w * xf.y;
        ds += w;
    }

    float inv = 1.f / ds;
    float2 bf = load2(bias, l, isbf);
    float o0 = a0 * inv + bf.x;
    float o1 = a1 * inv + bf.y;
    if (isbf) {
        bf162 o;
        o.x = __float2bfloat16(o0);
        o.y = __float2bfloat16(o1);
        ((bf162*)out)[(size_t)d * 64 + l] = o;
    } else {
        ((float2*)out)[(size_t)d * 64 + l] = make_float2(o0, o1);
    }
}

extern "C" void kernel_launch(void* const* d_in, const int* in_sizes, int n_in,
                              void* d_out, int out_size, void* d_ws, size_t ws_size,
                              hipStream_t stream)
{
    const void* x     = d_in[0];
    const int*  ei    = (const int*)d_in[1];
    const void* W     = d_in[2];
    const void* bproj = d_in[3];
    const void* atts  = d_in[4];
    const void* attd  = d_in[5];
    const void* bias  = d_in[6];

    // workspace layout (~41 MB), all segments 16B-aligned
    char* p = (char*)d_ws;
    int*    flag     = (int*)p;    p += 16;
    bf16*   xh       = (bf16*)p;   p += (size_t)NN * DIM * sizeof(bf16);
    float*  asrc     = (float*)p;  p += (size_t)NN * HEADS * sizeof(float);
    float*  adst     = (float*)p;  p += (size_t)NN * HEADS * sizeof(float);
    int*    rowstart = (int*)p;    p += (size_t)(NN + 1) * sizeof(int) + 12;
    int*    esrc     = (int*)p;    p += (size_t)ETOT * sizeof(int);
    int*    btot     = (int*)p;    p += 256 * sizeof(int);
    int*    gcur     = (int*)p;    p += 256 * sizeof(int);
    bf16*   waug     = (bf16*)p;   p += 16 * 128 * sizeof(bf16);
    float*  wc       = (float*)p;  p += 16 * sizeof(float);

    // zero btot + gcur (contiguous 2 KB)
    hipMemsetAsync(btot, 0, 512 * sizeof(int), stream);

    aug_count_kernel<<<B2 + 1, 256, 0, stream>>>(W, bproj, atts, attd, flag,
                                                 waug, wc, ei, btot);
    proj_scatter_kernel<<<PROJ_BLKS + B1, 256, 0, stream>>>(x, W, bproj, waug, wc,
                                                            flag, xh, asrc, adst,
                                                            ei, btot, gcur, esrc);
    csr_bucket_kernel<<<NBUK, 256, 0, stream>>>(btot, esrc, rowstart);
    gather_kernel<<<(NN + 3) / 4, 256, 0, stream>>>(rowstart, esrc, asrc, adst,
                                                    xh, bias, flag, d_out);
}

// Round 9
// 273.721 us; speedup vs baseline: 2.4633x; 1.0001x over previous
//
#include <hip/hip_runtime.h>
#include <hip/hip_bf16.h>

typedef __hip_bfloat16 bf16;
typedef __hip_bfloat162 bf162;
typedef __attribute__((ext_vector_type(8))) short short8;   // 8 bf16 (4 VGPRs)
typedef __attribute__((ext_vector_type(4))) float f32x4;    // MFMA C/D

#define NN 100000
#define NE 1600000
#define ETOT (NE + NN)
#define DIM 128
#define HEADS 8

// ---- bucket-sort CSR build parameters ----
#define BSH 8                                   // bucket = dest >> 8 (256 dests)
#define NBUK ((NN + 255) >> BSH)                // 391
#define DPB (1 << BSH)                          // 256 dests per bucket
#define EPB 2048                                // edges per scatter block
#define B1 ((ETOT + EPB - 1) / EPB)             // 831 scatter blocks
#define EPB2 8192                               // edges per count block
#define B2 ((ETOT + EPB2 - 1) / EPB2)           // 208 count blocks
#define MAXPER 20                               // regs/thread in bucket kernel
                                                // cap 5120 = mean 4352 + 11.6 sigma
#define PROJ_BLKS ((NN + 63) / 64)              // 1563

__device__ __forceinline__ float lrelu(float v) { return v > 0.f ? v : 0.2f * v; }

__device__ __forceinline__ float load1(const void* p, int i, int isbf) {
    return isbf ? __bfloat162float(((const bf16*)p)[i]) : ((const float*)p)[i];
}
__device__ __forceinline__ float2 load2(const void* p, size_t pairIdx, int isbf) {
    if (isbf) return __bfloat1622float2(((const bf162*)p)[pairIdx]);
    return ((const float2*)p)[pairIdx];
}
__device__ __forceinline__ short f2bf(float f) {
    bf16 h = __float2bfloat16(f);
    return *reinterpret_cast<short*>(&h);
}

// exclusive scan of btot[NBUK] -> bb[] in LDS; 2 elements per thread
// (handles NBUK up to 512).  One 256-thread block.
__device__ __forceinline__ void scan_btot(const int* __restrict__ btot,
                                          int* __restrict__ bb, int* __restrict__ wt4)
{
    const int t = threadIdx.x;
    const int v0 = (2 * t     < NBUK) ? btot[2 * t]     : 0;
    const int v1 = (2 * t + 1 < NBUK) ? btot[2 * t + 1] : 0;
    const int s = v0 + v1;
    const int l = t & 63, w = t >> 6;
    int inc = s;
    #pragma unroll
    for (int off = 1; off < 64; off <<= 1) {
        int u = __shfl_up(inc, off);
        if (l >= off) inc += u;
    }
    if (l == 63) wt4[w] = inc;
    __syncthreads();
    int add = 0;
    #pragma unroll
    for (int i = 0; i < 4; ++i) if (i < w) add += wt4[i];
    const int ex = add + inc - s;
    if (2 * t     < NBUK) bb[2 * t]     = ex;
    if (2 * t + 1 < NBUK) bb[2 * t + 1] = ex + v0;
    __syncthreads();
}

// ---------------------------------------------------------------------------
// K1 (launch 2): heterogeneous {count || aug}.
//   blocks [0, B2)  : coarse-bucket count, LDS hist -> NBUK global atomicAdds
//   block  B2       : dtype detect + augmented weight rows (round-5 proven)
// btot/gcur are zeroed by the preceding hipMemsetAsync.
// ---------------------------------------------------------------------------
__global__ __launch_bounds__(256) void aug_count_kernel(
    const void* __restrict__ W, const void* __restrict__ bproj,
    const void* __restrict__ atts, const void* __restrict__ attd,
    int* __restrict__ flag, bf16* __restrict__ waug, float* __restrict__ wc,
    const int* __restrict__ ei, int* __restrict__ btot)
{
    __shared__ char smem[32768 + 2048];
    const int tid = threadIdx.x;

    if (blockIdx.x < B2) {
        // ===================== count half =====================
        int* cnt = (int*)smem;
        for (int i = tid; i < NBUK; i += 256) cnt[i] = 0;
        __syncthreads();
        const int base = blockIdx.x * EPB2;
        #pragma unroll
        for (int it = 0; it < EPB2 / 1024; ++it) {
            const int e = base + it * 1024 + tid * 4;   // ETOT%4==0, NE%4==0
            if (e < ETOT) {
                int4 d4;
                if (e < NE) {
                    d4 = *(const int4*)(ei + NE + e);
                } else {
                    d4.x = e - NE; d4.y = d4.x + 1; d4.z = d4.x + 2; d4.w = d4.x + 3;
                }
                atomicAdd(&cnt[d4.x >> BSH], 1);
                atomicAdd(&cnt[d4.y >> BSH], 1);
                atomicAdd(&cnt[d4.z >> BSH], 1);
                atomicAdd(&cnt[d4.w >> BSH], 1);
            }
        }
        __syncthreads();
        for (int k = tid; k < NBUK; k += 256) {
            const int c = cnt[k];
            if (c) atomicAdd(&btot[k], c);
        }
        return;
    }

    // ===================== aug half (block B2) =====================
    bf16*  Wl  = (bf16*)smem;                 // 32 KB
    float* av  = (float*)(smem + 32768);      // 1 KB: atts | attd
    float* red = av + 256;                    // 1 KB

    // ---- detect ----
    {
        const bf16* wb = (const bf16*)W;
        float m = 0.f;
        for (int i = tid; i < 8192; i += 256) {
            float v = fabsf(__bfloat162float(wb[i]));
            if (!(v < 1e30f)) v = 1e30f;
            m = fmaxf(m, v);
        }
        red[tid] = m;
        __syncthreads();
        for (int s = 128; s > 0; s >>= 1) {
            if (tid < s) red[tid] = fmaxf(red[tid], red[tid + s]);
            __syncthreads();
        }
    }
    const int isbf = (red[0] < 1.0f) ? 1 : 0;
    if (tid == 0) *flag = isbf;

    // ---- aug ----
    for (int i = tid; i < 2048; i += 256) {       // 2048 chunks of 8 bf16
        short8 v;
        if (isbf) {
            v = ((const short8*)W)[i];
        } else {
            const float* wp = (const float*)W + (size_t)i * 8;
            #pragma unroll
            for (int j = 0; j < 8; ++j) v[j] = f2bf(wp[j]);
        }
        ((short8*)Wl)[i] = v;
    }
    av[tid & 255] = (tid < 128) ? load1(atts, tid, isbf)
                                : load1(attd, tid - 128, isbf);
    __syncthreads();

    #pragma unroll
    for (int it = 0; it < 8; ++it) {
        const int o = tid + it * 256;             // 0..2047
        const int row = o >> 7, col = o & 127;
        const int h = row & 7;
        const int ao = (row < 8) ? 0 : 128;
        float s = 0.f;
        #pragma unroll
        for (int t = 0; t < 16; ++t)
            s += av[ao + h * 16 + t] * __bfloat162float(Wl[(h * 16 + t) * 128 + col]);
        waug[o] = __float2bfloat16(s);
    }
    if (tid < 16) {
        const int h = tid & 7;
        const int ao = (tid < 8) ? 0 : 128;
        float s = 0.f;
        #pragma unroll
        for (int t = 0; t < 16; ++t)
            s += load1(bproj, h * 16 + t, isbf) * av[ao + h * 16 + t];
        wc[tid] = s;
    }
}

// ---------------------------------------------------------------------------
// K2 (launch 3): heterogeneous {proj || scatter} (round-8 proven).
//   blocks [0, PROJ_BLKS)       : MFMA projection
//   blocks [PROJ_BLKS, +B1)     : chunk-reservation scatter (packed u32:
//     src | (dest&255)<<17)
// ---------------------------------------------------------------------------
__global__ __launch_bounds__(256) void proj_scatter_kernel(
    const void* __restrict__ x, const void* __restrict__ W,
    const void* __restrict__ bproj, const bf16* __restrict__ waug,
    const float* __restrict__ wc, const int* __restrict__ flag,
    bf16* __restrict__ xh, float* __restrict__ asrc, float* __restrict__ adst,
    const int* __restrict__ ei, const int* __restrict__ btot,
    int* __restrict__ gcur, int* __restrict__ esrc)
{
    __shared__ short8 Wf[2304];                 // 36 KB (proj) / scatter overlay
    __shared__ float bsh[DIM], csh[16];

    const int tid = threadIdx.x;

    if (blockIdx.x >= PROJ_BLKS) {
        // ===================== scatter half =====================
        int* hist = (int*)Wf;                   // [NBUK]
        int* cur  = hist + NBUK;                // [NBUK]
        int* bb   = cur + NBUK;                 // [NBUK]
        int* wt4  = bb + NBUK;                  // [4]
        const int b = blockIdx.x - PROJ_BLKS;

        for (int i = tid; i < NBUK; i += 256) hist[i] = 0;
        __syncthreads();

        const int base = b * EPB;
        int4 s4[2], d4[2];
        int valid[2];
        #pragma unroll
        for (int it = 0; it < 2; ++it) {
            const int e = base + it * 1024 + tid * 4;
            valid[it] = (e < ETOT);
            if (valid[it]) {
                if (e < NE) {
                    s4[it] = *(const int4*)(ei + e);
                    d4[it] = *(const int4*)(ei + NE + e);
                } else {
                    s4[it].x = e - NE; s4[it].y = s4[it].x + 1;
                    s4[it].z = s4[it].x + 2; s4[it].w = s4[it].x + 3;
                    d4[it] = s4[it];
                }
                atomicAdd(&hist[d4[it].x >> BSH], 1);
                atomicAdd(&hist[d4[it].y >> BSH], 1);
                atomicAdd(&hist[d4[it].z >> BSH], 1);
                atomicAdd(&hist[d4[it].w >> BSH], 1);
            }
        }
        __syncthreads();

        scan_btot(btot, bb, wt4);               // bb = bucket global bases

        // reserve a contiguous chunk per bucket with edges in this block
        for (int k = tid; k < NBUK; k += 256) {
            const int c = hist[k];
            cur[k] = c ? (bb[k] + atomicAdd(&gcur[k], c)) : 0;
        }
        __syncthreads();

        #pragma unroll
        for (int it = 0; it < 2; ++it) {
            if (valid[it]) {
                const int p0 = atomicAdd(&cur[d4[it].x >> BSH], 1);
                const int p1 = atomicAdd(&cur[d4[it].y >> BSH], 1);
                const int p2 = atomicAdd(&cur[d4[it].z >> BSH], 1);
                const int p3 = atomicAdd(&cur[d4[it].w >> BSH], 1);
                esrc[p0] = s4[it].x | ((d4[it].x & (DPB - 1)) << 17);
                esrc[p1] = s4[it].y | ((d4[it].y & (DPB - 1)) << 17);
                esrc[p2] = s4[it].z | ((d4[it].z & (DPB - 1)) << 17);
                esrc[p3] = s4[it].w | ((d4[it].w & (DPB - 1)) << 17);
            }
        }
        return;
    }

    // ===================== proj half (round-7 proven body) =====================
    const int isbf = *flag;

    for (int c = tid; c < 2048; c += 256) {
        int j = c >> 4, kc = c & 15;
        int kb = kc >> 2, quad = kc & 3;
        int lane = quad * 16 + (j & 15);
        int jt = j >> 4;
        short8 v;
        if (isbf) {
            v = ((const short8*)W)[c];          // 8 bf16 at W[j][kc*8]
        } else {
            const float* wp = (const float*)W + (size_t)j * DIM + kc * 8;
            #pragma unroll
            for (int i = 0; i < 8; ++i) v[i] = f2bf(wp[i]);
        }
        Wf[(jt * 4 + kb) * 64 + lane] = v;
    }
    {   // augmented tile (16 rows x 128 k), already bf16
        int c = tid;
        if (c < 256) {
            int j2 = c >> 4, kc = c & 15;
            int kb = kc >> 2, quad = kc & 3;
            Wf[(32 + kb) * 64 + quad * 16 + j2] = ((const short8*)waug)[c];
        }
    }
    if (tid < DIM) bsh[tid] = load1(bproj, tid, isbf);
    if (tid < 16)  csh[tid] = wc[tid];
    __syncthreads();

    const int w = tid >> 6;
    const int l = tid & 63;
    const int quad = l >> 4, mr = l & 15;
    const int n0 = blockIdx.x * 64 + w * 16;    // wave's first node
    const int nArd = min(n0 + mr, NN - 1);      // clamped A-frag row

    short8 afr[4];
    if (isbf) {
        const short8* xp = (const short8*)x + (size_t)nArd * 16;
        #pragma unroll
        for (int kb = 0; kb < 4; ++kb) afr[kb] = xp[kb * 4 + quad];
    } else {
        const float* xp = (const float*)x + (size_t)nArd * DIM;
        #pragma unroll
        for (int kb = 0; kb < 4; ++kb) {
            const float* cp = xp + kb * 32 + quad * 8;
            float4 c0 = *(const float4*)cp;
            float4 c1 = *(const float4*)(cp + 4);
            short8 v;
            v[0] = f2bf(c0.x); v[1] = f2bf(c0.y); v[2] = f2bf(c0.z); v[3] = f2bf(c0.w);
            v[4] = f2bf(c1.x); v[5] = f2bf(c1.y); v[6] = f2bf(c1.z); v[7] = f2bf(c1.w);
            afr[kb] = v;
        }
    }

    // ---- MFMA phase: keep all 8 xh-tiles in registers ----
    f32x4 accs[8];
    #pragma unroll
    for (int jt = 0; jt < 8; ++jt) {
        f32x4 acc = {0.f, 0.f, 0.f, 0.f};
        #pragma unroll
        for (int kb = 0; kb < 4; ++kb) {
            short8 b = Wf[(jt * 4 + kb) * 64 + l];
            acc = __builtin_amdgcn_mfma_f32_16x16x32_bf16(afr[kb], b, acc, 0, 0, 0);
        }
        accs[jt] = acc;
    }
    f32x4 acca = {0.f, 0.f, 0.f, 0.f};
    #pragma unroll
    for (int kb = 0; kb < 4; ++kb) {
        short8 b = Wf[(32 + kb) * 64 + l];
        acca = __builtin_amdgcn_mfma_f32_16x16x32_bf16(afr[kb], b, acca, 0, 0, 0);
    }

    __syncthreads();                            // all waves done reading Wf

    // ---- stage 16x128 bf16 tile in LDS (stride 136 elems = 272B) ----
    bf16* sw = ((bf16*)Wf) + w * (16 * 136);    // 4352 B per wave
    #pragma unroll
    for (int jt = 0; jt < 8; ++jt) {
        const int jj = jt * 16 + mr;
        const float bv = bsh[jj];
        #pragma unroll
        for (int r = 0; r < 4; ++r)
            sw[(quad * 4 + r) * 136 + jj] = __float2bfloat16(accs[jt][r] + bv);
    }
    // ---- coalesced write-back: 4 x short8 per lane ----
    #pragma unroll
    for (int g = 0; g < 4; ++g) {
        const int row = g * 4 + (l >> 4);       // 0..15
        const int n = n0 + row;
        if (n < NN)
            *((short8*)(xh + (size_t)n * DIM) + (l & 15)) =
                *(const short8*)(sw + row * 136 + (l & 15) * 8);
    }

    // ---- asrc/adst from the augmented tile ----
    {
        const float cst = csh[mr];
        #pragma unroll
        for (int r = 0; r < 4; ++r) {
            const int n = n0 + quad * 4 + r;
            if (n < NN) {
                float v = acca[r] + cst;
                if (mr < 8) asrc[n * HEADS + mr] = v;
                else        adst[n * HEADS + (mr - 8)] = v;
            }
        }
    }
}

// ---------------------------------------------------------------------------
// K3 (launch 4): in-bucket sort + rowstart write.
// BSH=8: 391 blocks (1.5/CU co-residency vs 0.77 before), half the serial
// edges per block, 256 dests -> 1 scan element/thread.  LDS histogram split
// into 2 banks (waves 0-1 / 2-3) to halve same-slot atomic contention.
// ---------------------------------------------------------------------------
__global__ __launch_bounds__(256) void csr_bucket_kernel(const int* __restrict__ btot,
                                                         int* __restrict__ esrc,
                                                         int* __restrict__ rowstart)
{
    __shared__ int hist[2 * DPB];               // 2 contention banks
    __shared__ int pre[DPB];
    __shared__ int bb[NBUK + 1];
    __shared__ int wt4[4];
    const int k = blockIdx.x, t = threadIdx.x;

    hist[t] = 0;
    hist[t + DPB] = 0;
    __syncthreads();

    scan_btot(btot, bb, wt4);
    const int start = bb[k];
    const int end = start + btot[k];
    if (k == 0 && t == 0) rowstart[NN] = ETOT;

    const int bank = (t >> 7) * DPB;            // waves 0-1 -> 0, waves 2-3 -> DPB

    // load bucket to registers (statically indexed -> stays in VGPRs)
    int v[MAXPER];
    #pragma unroll
    for (int j = 0; j < MAXPER; ++j) {
        const int idx = start + j * 256 + t;
        v[j] = (idx < end) ? esrc[idx] : -1;
    }
    #pragma unroll
    for (int j = 0; j < MAXPER; ++j)
        if (v[j] >= 0) atomicAdd(&hist[bank + ((v[j] >> 17) & (DPB - 1))], 1);
    __syncthreads();

    // exclusive scan of 256 merged dest counts (1 per thread)
    const int hc = hist[t] + hist[t + DPB];
    const int l = t & 63, w = t >> 6;
    int inc = hc;
    #pragma unroll
    for (int off = 1; off < 64; off <<= 1) {
        int u = __shfl_up(inc, off);
        if (l >= off) inc += u;
    }
    if (l == 63) wt4[w] = inc;
    __syncthreads();
    int add = 0;
    #pragma unroll
    for (int i = 0; i < 4; ++i) if (i < w) add += wt4[i];
    const int ex = add + inc - hc;
    pre[t] = ex;

    // rowstart for this bucket's dest range (256 dests, 1 per thread)
    const int d0 = (k << BSH) + t;
    if (d0 < NN) rowstart[d0] = start + ex;
    __syncthreads();

    // in-place scatter: plain src (block owns [start,end) exclusively)
    #pragma unroll
    for (int j = 0; j < MAXPER; ++j) {
        if (v[j] >= 0) {
            const int pos = atomicAdd(&pre[(v[j] >> 17) & (DPB - 1)], 1);
            esrc[start + pos] = v[j] & 0x1FFFF;
        }
    }
}

// ---------------------------------------------------------------------------
// K4 (launch 5): gather-aggregate (unchanged control).
// ---------------------------------------------------------------------------
__global__ __launch_bounds__(256) void gather_kernel(
    const int* __restrict__ rowstart, const int* __restrict__ esrc,
    const float* __restrict__ asrc, const float* __restrict__ adst,
    const bf16* __restrict__ xh, const void* __restrict__ bias,
    const int* __restrict__ flag, void* __restrict__ out)
{
    const int d = blockIdx.x * 4 + (threadIdx.x >> 6);
    if (d >= NN) return;
    const int l = threadIdx.x & 63;
    const int h = l >> 3;
    const int isbf = *flag;

    const float ad = adst[d * HEADS + h];
    const int r0 = rowstart[d], r1 = rowstart[d + 1];
    const bf162* __restrict__ xrow = (const bf162*)xh;
    float a0 = 0.f, a1 = 0.f, ds = 0.f;

    int p = r0;
    for (; p + 8 <= r1; p += 8) {
        int s[8];
        #pragma unroll
        for (int j = 0; j < 8; ++j) s[j] = esrc[p + j];
        float v[8];
        #pragma unroll
        for (int j = 0; j < 8; ++j) v[j] = asrc[(unsigned)s[j] * HEADS + h];
        float2 xv[8];
        #pragma unroll
        for (int j = 0; j < 8; ++j)
            xv[j] = __bfloat1622float2(xrow[(unsigned)s[j] * 64u + (unsigned)l]);
        #pragma unroll
        for (int j = 0; j < 8; ++j) {
            float wj = __expf(lrelu(v[j] + ad));
            a0 += wj * xv[j].x;
            a1 += wj * xv[j].y;
            ds += wj;
        }
    }
    for (; p + 4 <= r1; p += 4) {
        int s0 = esrc[p + 0], s1 = esrc[p + 1], s2 = esrc[p + 2], s3 = esrc[p + 3];
        float v0 = asrc[(unsigned)s0 * HEADS + h];
        float v1 = asrc[(unsigned)s1 * HEADS + h];
        float v2 = asrc[(unsigned)s2 * HEADS + h];
        float v3 = asrc[(unsigned)s3 * HEADS + h];
        float2 x0 = __bfloat1622float2(xrow[(unsigned)s0 * 64u + (unsigned)l]);
        float2 x1 = __bfloat1622float2(xrow[(unsigned)s1 * 64u + (unsigned)l]);
        float2 x2 = __bfloat1622float2(xrow[(unsigned)s2 * 64u + (unsigned)l]);
        float2 x3 = __bfloat1622float2(xrow[(unsigned)s3 * 64u + (unsigned)l]);
        float w0 = __expf(lrelu(v0 + ad));
        float w1 = __expf(lrelu(v1 + ad));
        float w2 = __expf(lrelu(v2 + ad));
        float w3 = __expf(lrelu(v3 + ad));
        a0 += w0 * x0.x + w1 * x1.x + w2 * x2.x + w3 * x3.x;
        a1 += w0 * x0.y + w1 * x1.y + w2 * x2.y + w3 * x3.y;
        ds += (w0 + w1) + (w2 + w3);
    }
    for (; p < r1; ++p) {
        int s = esrc[p];
        float w = __expf(lrelu(asrc[(unsigned)s * HEADS + h] + ad));
        float2 xf = __bfloat1622float2(xrow[(unsigned)s * 64u + (unsigned)l]);
        a0 += w * xf.x;
        a1 += w * xf.y;
        ds += w;
    }

    float inv = 1.f / ds;
    float2 bf = load2(bias, l, isbf);
    float o0 = a0 * inv + bf.x;
    float o1 = a1 * inv + bf.y;
    if (isbf) {
        bf162 o;
        o.x = __float2bfloat16(o0);
        o.y = __float2bfloat16(o1);
        ((bf162*)out)[(size_t)d * 64 + l] = o;
    } else {
        ((float2*)out)[(size_t)d * 64 + l] = make_float2(o0, o1);
    }
}

extern "C" void kernel_launch(void* const* d_in, const int* in_sizes, int n_in,
                              void* d_out, int out_size, void* d_ws, size_t ws_size,
                              hipStream_t stream)
{
    const void* x     = d_in[0];
    const int*  ei    = (const int*)d_in[1];
    const void* W     = d_in[2];
    const void* bproj = d_in[3];
    const void* atts  = d_in[4];
    const void* attd  = d_in[5];
    const void* bias  = d_in[6];

    // workspace layout (~41 MB), all segments 16B-aligned
    char* p = (char*)d_ws;
    int*    flag     = (int*)p;    p += 16;
    bf16*   xh       = (bf16*)p;   p += (size_t)NN * DIM * sizeof(bf16);
    float*  asrc     = (float*)p;  p += (size_t)NN * HEADS * sizeof(float);
    float*  adst     = (float*)p;  p += (size_t)NN * HEADS * sizeof(float);
    int*    rowstart = (int*)p;    p += (size_t)(NN + 1) * sizeof(int) + 12;
    int*    esrc     = (int*)p;    p += (size_t)ETOT * sizeof(int);
    int*    btot     = (int*)p;    p += 512 * sizeof(int);
    int*    gcur     = (int*)p;    p += 512 * sizeof(int);
    bf16*   waug     = (bf16*)p;   p += 16 * 128 * sizeof(bf16);
    float*  wc       = (float*)p;  p += 16 * sizeof(float);

    // zero btot + gcur (contiguous 4 KB)
    hipMemsetAsync(btot, 0, 1024 * sizeof(int), stream);

    aug_count_kernel<<<B2 + 1, 256, 0, stream>>>(W, bproj, atts, attd, flag,
                                                 waug, wc, ei, btot);
    proj_scatter_kernel<<<PROJ_BLKS + B1, 256, 0, stream>>>(x, W, bproj, waug, wc,
                                                            flag, xh, asrc, adst,
                                                            ei, btot, gcur, esrc);
    csr_bucket_kernel<<<NBUK, 256, 0, stream>>>(btot, esrc, rowstart);
    gather_kernel<<<(NN + 3) / 4, 256, 0, stream>>>(rowstart, esrc, asrc, adst,
                                                    xh, bias, flag, d_out);
}